// Round 3
// baseline (572.213 us; speedup 1.0000x reference)
//
#include <hip/hip_runtime.h>
#include <math.h>

#define ALPHA 1.57f
#define BN_EPS 1e-5f

// ---------------- Stage 1: conv1(3->16) + BN + ReLU + pool2 ----------------
// x (1024,3,64,64) -> g1 (1024,16,32,32)
__global__ __launch_bounds__(256)
void stage1_kernel(const float* __restrict__ x,
                   const float* __restrict__ w,    // (16,3,3,3)
                   const float* __restrict__ cb,   // (16)
                   const float* __restrict__ bg,
                   const float* __restrict__ bb,
                   const float* __restrict__ bm,
                   const float* __restrict__ bv,
                   float* __restrict__ g1)
{
    __shared__ float simg[3*66*66];   // zero-padded image
    __shared__ float sscale[16];
    __shared__ float sshift[16];
    const int b = blockIdx.x;
    const int t = threadIdx.x;

    for (int i = t; i < 3*66*66; i += 256) simg[i] = 0.f;
    if (t < 16) {
        float inv = bg[t] * rsqrtf(bv[t] + BN_EPS);
        sscale[t] = inv;
        sshift[t] = cb[t]*inv + bb[t] - bm[t]*inv;
    }
    __syncthreads();

    const float4* xin = reinterpret_cast<const float4*>(x + (size_t)b*12288);
    #pragma unroll
    for (int k = 0; k < 12; ++k) {
        int i4 = t + k*256;            // 0..3071
        float4 vv = xin[i4];
        int e  = i4*4;                 // multiple of 4, rows of 64 -> no crossing
        int ci = e >> 12;
        int rem = e & 4095;
        int y  = rem >> 6;
        int xx = rem & 63;
        float* dst = &simg[ci*4356 + (y+1)*66 + (xx+1)];
        dst[0]=vv.x; dst[1]=vv.y; dst[2]=vv.z; dst[3]=vv.w;
    }
    __syncthreads();

    for (int it = 0; it < 4; ++it) {
        int pos = it*256 + t;          // pooled position 0..1023
        int py = pos >> 5, px = pos & 31;
        float acc[16][4];
        #pragma unroll
        for (int c = 0; c < 16; ++c) {
            acc[c][0]=0.f; acc[c][1]=0.f; acc[c][2]=0.f; acc[c][3]=0.f;
        }
        #pragma unroll
        for (int ci = 0; ci < 3; ++ci) {
            float p[16];
            const float* sp = &simg[ci*4356 + (2*py)*66 + 2*px];
            #pragma unroll
            for (int i = 0; i < 4; ++i)
                #pragma unroll
                for (int j = 0; j < 4; ++j)
                    p[i*4+j] = sp[i*66+j];
            #pragma unroll
            for (int co = 0; co < 16; ++co) {
                const float* wp = &w[co*27 + ci*9];   // block-uniform -> s_load
                #pragma unroll
                for (int ky = 0; ky < 3; ++ky)
                    #pragma unroll
                    for (int kx = 0; kx < 3; ++kx) {
                        float wv = wp[ky*3+kx];
                        acc[co][0] = fmaf(wv, p[ ky   *4+kx  ], acc[co][0]);
                        acc[co][1] = fmaf(wv, p[ ky   *4+kx+1], acc[co][1]);
                        acc[co][2] = fmaf(wv, p[(ky+1)*4+kx  ], acc[co][2]);
                        acc[co][3] = fmaf(wv, p[(ky+1)*4+kx+1], acc[co][3]);
                    }
            }
        }
        #pragma unroll
        for (int co = 0; co < 16; ++co) {
            float sc = sscale[co], sh = sshift[co];
            float v0 = fmaf(acc[co][0], sc, sh);
            float v1 = fmaf(acc[co][1], sc, sh);
            float v2 = fmaf(acc[co][2], sc, sh);
            float v3 = fmaf(acc[co][3], sc, sh);
            float mx = fmaxf(fmaxf(v0,v1), fmaxf(v2,v3));
            g1[(((size_t)b*16 + co) << 10) + pos] = fmaxf(mx, 0.f);
        }
    }
}

// ---------------- Stage 2: conv2(16->32) + BN + ReLU + pool2 ----------------
// g1 (1024,16,32,32) -> g2 (1024,32,16,16)
__global__ __launch_bounds__(256)
void stage2_kernel(const float* __restrict__ g1,
                   const float* __restrict__ w,    // (32,16,3,3)
                   const float* __restrict__ cb,
                   const float* __restrict__ bg,
                   const float* __restrict__ bb,
                   const float* __restrict__ bm,
                   const float* __restrict__ bv,
                   float* __restrict__ g2)
{
    __shared__ float simg[16*34*34];  // 18496 floats, zero-padded
    __shared__ float sscale[32];
    __shared__ float sshift[32];
    const int b = blockIdx.x;
    const int t = threadIdx.x;

    for (int i = t; i < 16*34*34; i += 256) simg[i] = 0.f;
    if (t < 32) {
        float inv = bg[t] * rsqrtf(bv[t] + BN_EPS);
        sscale[t] = inv;
        sshift[t] = cb[t]*inv + bb[t] - bm[t]*inv;
    }
    __syncthreads();

    const float4* gin = reinterpret_cast<const float4*>(g1 + (size_t)b*16384);
    #pragma unroll
    for (int k = 0; k < 16; ++k) {
        int i4 = t + k*256;            // 0..4095
        float4 vv = gin[i4];
        int e  = i4*4;
        int ci = e >> 10;
        int rem = e & 1023;
        int y  = rem >> 5;
        int xx = rem & 31;
        float* dst = &simg[ci*1156 + (y+1)*34 + (xx+1)];
        dst[0]=vv.x; dst[1]=vv.y; dst[2]=vv.z; dst[3]=vv.w;
    }
    __syncthreads();

    const int gg   = __builtin_amdgcn_readfirstlane(t >> 6);  // wave -> co group
    const int lane = t & 63;

    for (int it = 0; it < 4; ++it) {
        int pos = it*64 + lane;        // pooled position 0..255
        int py = pos >> 4, px = pos & 15;
        float acc[8][4];
        #pragma unroll
        for (int c = 0; c < 8; ++c) {
            acc[c][0]=0.f; acc[c][1]=0.f; acc[c][2]=0.f; acc[c][3]=0.f;
        }
        for (int ci = 0; ci < 16; ++ci) {
            float p[16];
            const float* sp = &simg[ci*1156 + (2*py)*34 + 2*px];
            #pragma unroll
            for (int i = 0; i < 4; ++i)
                #pragma unroll
                for (int j = 0; j < 4; ++j)
                    p[i*4+j] = sp[i*34+j];
            #pragma unroll
            for (int c = 0; c < 8; ++c) {
                const float* wp = &w[((gg*8 + c)*16 + ci)*9];  // wave-uniform -> s_load
                #pragma unroll
                for (int ky = 0; ky < 3; ++ky)
                    #pragma unroll
                    for (int kx = 0; kx < 3; ++kx) {
                        float wv = wp[ky*3+kx];
                        acc[c][0] = fmaf(wv, p[ ky   *4+kx  ], acc[c][0]);
                        acc[c][1] = fmaf(wv, p[ ky   *4+kx+1], acc[c][1]);
                        acc[c][2] = fmaf(wv, p[(ky+1)*4+kx  ], acc[c][2]);
                        acc[c][3] = fmaf(wv, p[(ky+1)*4+kx+1], acc[c][3]);
                    }
            }
        }
        #pragma unroll
        for (int c = 0; c < 8; ++c) {
            int co = gg*8 + c;
            float sc = sscale[co], sh = sshift[co];
            float v0 = fmaf(acc[c][0], sc, sh);
            float v1 = fmaf(acc[c][1], sc, sh);
            float v2 = fmaf(acc[c][2], sc, sh);
            float v3 = fmaf(acc[c][3], sc, sh);
            float mx = fmaxf(fmaxf(v0,v1), fmaxf(v2,v3));
            g2[(((size_t)b*32 + co) << 8) + pos] = fmaxf(mx, 0.f);
        }
    }
}

// ------- Stage 3: conv3(32->64)+BN+ReLU+pool2 + proj + quantum + cls -------
// g2 (1024,32,16,16) -> out (1024,10)
__global__ __launch_bounds__(256)
void stage3_kernel(const float* __restrict__ g2,
                   const float* __restrict__ w,    // (64,32,3,3)
                   const float* __restrict__ cb,
                   const float* __restrict__ bg,
                   const float* __restrict__ bb,
                   const float* __restrict__ bm,
                   const float* __restrict__ bv,
                   const float* __restrict__ pw,   // (4,4096)
                   const float* __restrict__ pb,   // (4)
                   const float* __restrict__ cw,   // (10,10)
                   const float* __restrict__ cbias,// (10)
                   float* __restrict__ out)
{
    __shared__ float simg[32*18*18];  // 10368 floats, zero-padded
    __shared__ float fbuf[4096];      // flattened features (C,H,W)
    __shared__ float sscale[64];
    __shared__ float sshift[64];
    __shared__ float red[4][4];
    const int b = blockIdx.x;
    const int t = threadIdx.x;

    for (int i = t; i < 32*18*18; i += 256) simg[i] = 0.f;
    if (t < 64) {
        float inv = bg[t] * rsqrtf(bv[t] + BN_EPS);
        sscale[t] = inv;
        sshift[t] = cb[t]*inv + bb[t] - bm[t]*inv;
    }
    __syncthreads();

    const float4* gin = reinterpret_cast<const float4*>(g2 + (size_t)b*8192);
    #pragma unroll
    for (int k = 0; k < 8; ++k) {
        int i4 = t + k*256;            // 0..2047
        float4 vv = gin[i4];
        int e  = i4*4;
        int ci = e >> 8;
        int rem = e & 255;
        int y  = rem >> 4;
        int xx = rem & 15;
        float* dst = &simg[ci*324 + (y+1)*18 + (xx+1)];
        dst[0]=vv.x; dst[1]=vv.y; dst[2]=vv.z; dst[3]=vv.w;
    }
    __syncthreads();

    const int gg   = __builtin_amdgcn_readfirstlane(t >> 6);  // wave -> 16 co's
    const int lane = t & 63;
    {
        int py = lane >> 3, px = lane & 7;   // pooled 8x8
        float acc[16][4];
        #pragma unroll
        for (int c = 0; c < 16; ++c) {
            acc[c][0]=0.f; acc[c][1]=0.f; acc[c][2]=0.f; acc[c][3]=0.f;
        }
        for (int ci = 0; ci < 32; ++ci) {
            float p[16];
            const float* sp = &simg[ci*324 + (2*py)*18 + 2*px];
            #pragma unroll
            for (int i = 0; i < 4; ++i)
                #pragma unroll
                for (int j = 0; j < 4; ++j)
                    p[i*4+j] = sp[i*18+j];
            #pragma unroll
            for (int c = 0; c < 16; ++c) {
                const float* wp = &w[((gg*16 + c)*32 + ci)*9];  // wave-uniform
                #pragma unroll
                for (int ky = 0; ky < 3; ++ky)
                    #pragma unroll
                    for (int kx = 0; kx < 3; ++kx) {
                        float wv = wp[ky*3+kx];
                        acc[c][0] = fmaf(wv, p[ ky   *4+kx  ], acc[c][0]);
                        acc[c][1] = fmaf(wv, p[ ky   *4+kx+1], acc[c][1]);
                        acc[c][2] = fmaf(wv, p[(ky+1)*4+kx  ], acc[c][2]);
                        acc[c][3] = fmaf(wv, p[(ky+1)*4+kx+1], acc[c][3]);
                    }
            }
        }
        #pragma unroll
        for (int c = 0; c < 16; ++c) {
            int co = gg*16 + c;
            float sc = sscale[co], sh = sshift[co];
            float v0 = fmaf(acc[c][0], sc, sh);
            float v1 = fmaf(acc[c][1], sc, sh);
            float v2 = fmaf(acc[c][2], sc, sh);
            float v3 = fmaf(acc[c][3], sc, sh);
            float mx = fmaxf(fmaxf(v0,v1), fmaxf(v2,v3));
            fbuf[co*64 + lane] = fmaxf(mx, 0.f);
        }
    }
    __syncthreads();

    // projection z = f @ proj_w.T + proj_b   (4 outputs)
    float z0=0.f, z1=0.f, z2=0.f, z3=0.f;
    #pragma unroll
    for (int k = 0; k < 16; ++k) {
        int j = k*256 + t;
        float fv = fbuf[j];
        z0 = fmaf(fv, pw[        j], z0);
        z1 = fmaf(fv, pw[ 4096 + j], z1);
        z2 = fmaf(fv, pw[ 8192 + j], z2);
        z3 = fmaf(fv, pw[12288 + j], z3);
    }
    #pragma unroll
    for (int off = 32; off > 0; off >>= 1) {
        z0 += __shfl_down(z0, off);
        z1 += __shfl_down(z1, off);
        z2 += __shfl_down(z2, off);
        z3 += __shfl_down(z3, off);
    }
    if (lane == 0) { red[gg][0]=z0; red[gg][1]=z1; red[gg][2]=z2; red[gg][3]=z3; }
    __syncthreads();

    if (t == 0) {
        float z[4];
        #pragma unroll
        for (int p2 = 0; p2 < 4; ++p2)
            z[p2] = red[0][p2]+red[1][p2]+red[2][p2]+red[3][p2] + pb[p2];

        float qc[4], qs[4];
        #pragma unroll
        for (int k = 0; k < 4; ++k) {
            float h = 0.5f * ALPHA * z[k];
            qc[k] = cosf(h);
            qs[k] = sinf(h);
        }
        float st[16];
        #pragma unroll
        for (int j = 0; j < 16; ++j) {
            float v0 = ((j>>3)&1) ? qs[0] : qc[0];
            float v1 = ((j>>2)&1) ? qs[1] : qc[1];
            float v2 = ((j>>1)&1) ? qs[2] : qc[2];
            float v3 = ( j    &1) ? qs[3] : qc[3];
            st[j] = v0*v1*v2*v3;
        }
        // CNOT permutations (c,t) in (0,1),(1,2),(2,3),(3,0): state = state[perm]
        const int csrc[4] = {0,1,2,3};
        const int ctgt[4] = {1,2,3,0};
        #pragma unroll
        for (int pp = 0; pp < 4; ++pp) {
            float tmp[16];
            #pragma unroll
            for (int idx = 0; idx < 16; ++idx) {
                int bit = (idx >> (3 - csrc[pp])) & 1;
                int src = bit ? (idx ^ (1 << (3 - ctgt[pp]))) : idx;
                tmp[idx] = st[src];
            }
            #pragma unroll
            for (int idx = 0; idx < 16; ++idx) st[idx] = tmp[idx];
        }
        float feat[10];
        #pragma unroll
        for (int f = 0; f < 10; ++f) feat[f] = 0.f;
        #pragma unroll
        for (int j = 0; j < 16; ++j) {
            float pr = st[j]*st[j];
            float s0 = ((j>>3)&1) ? -1.f : 1.f;
            float s1 = ((j>>2)&1) ? -1.f : 1.f;
            float s2 = ((j>>1)&1) ? -1.f : 1.f;
            float s3 = ( j    &1) ? -1.f : 1.f;
            feat[0] += s0*pr;       feat[1] += s1*pr;
            feat[2] += s2*pr;       feat[3] += s3*pr;
            feat[4] += s0*s1*pr;    feat[5] += s0*s2*pr;
            feat[6] += s0*s3*pr;    feat[7] += s1*s2*pr;
            feat[8] += s1*s3*pr;    feat[9] += s2*s3*pr;
        }
        #pragma unroll
        for (int o = 0; o < 10; ++o) {
            float a = cbias[o];
            #pragma unroll
            for (int f = 0; f < 10; ++f) a = fmaf(feat[f], cw[o*10+f], a);
            out[(size_t)b*10 + o] = a;
        }
    }
}

extern "C" void kernel_launch(void* const* d_in, const int* in_sizes, int n_in,
                              void* d_out, int out_size, void* d_ws, size_t ws_size,
                              hipStream_t stream)
{
    // setup_inputs() dict order:
    //  0 x            (1024,3,64,64)
    //  1 conv1_w  2 conv1_b  3 conv2_w  4 conv2_b  5 conv3_w  6 conv3_b
    //  7 bn1_g  8 bn1_b  9 bn1_m 10 bn1_v
    // 11 bn2_g 12 bn2_b 13 bn2_m 14 bn2_v
    // 15 bn3_g 16 bn3_b 17 bn3_m 18 bn3_v
    // 19 proj_w 20 proj_b 21 cls_w 22 cls_b
    const float* x   = (const float*)d_in[0];
    const float* c1w = (const float*)d_in[1];
    const float* c1b = (const float*)d_in[2];
    const float* c2w = (const float*)d_in[3];
    const float* c2b = (const float*)d_in[4];
    const float* c3w = (const float*)d_in[5];
    const float* c3b = (const float*)d_in[6];
    const float* b1g = (const float*)d_in[7];
    const float* b1b = (const float*)d_in[8];
    const float* b1m = (const float*)d_in[9];
    const float* b1v = (const float*)d_in[10];
    const float* b2g = (const float*)d_in[11];
    const float* b2b = (const float*)d_in[12];
    const float* b2m = (const float*)d_in[13];
    const float* b2v = (const float*)d_in[14];
    const float* b3g = (const float*)d_in[15];
    const float* b3b = (const float*)d_in[16];
    const float* b3m = (const float*)d_in[17];
    const float* b3v = (const float*)d_in[18];
    const float* pw  = (const float*)d_in[19];
    const float* pb  = (const float*)d_in[20];
    const float* cw  = (const float*)d_in[21];
    const float* cbv = (const float*)d_in[22];

    float* g1 = (float*)d_ws;                             // 1024*16*32*32 fp32 = 64 MB
    float* g2 = (float*)((char*)d_ws + (size_t)67108864); // 1024*32*16*16 fp32 = 32 MB
    float* out = (float*)d_out;

    stage1_kernel<<<1024, 256, 0, stream>>>(x,  c1w, c1b, b1g, b1b, b1m, b1v, g1);
    stage2_kernel<<<1024, 256, 0, stream>>>(g1, c2w, c2b, b2g, b2b, b2m, b2v, g2);
    stage3_kernel<<<1024, 256, 0, stream>>>(g2, c3w, c3b, b3g, b3b, b3m, b3v,
                                            pw, pb, cw, cbv, out);
}

// Round 4
// 480.360 us; speedup vs baseline: 1.1912x; 1.1912x over previous
//
#include <hip/hip_runtime.h>
#include <math.h>

#define ALPHA 1.57f
#define BN_EPS 1e-5f

// ---------------- Stage 1: conv1(3->16) + BN + ReLU + pool2 ----------------
// x (1024,3,64,64) -> g1 (1024,16,32,32)
// v2: 2 blocks per image (half-image + halo), 8 co per wave, float2 LDS reads.
__global__ __launch_bounds__(256)
void stage1_kernel(const float* __restrict__ x,
                   const float* __restrict__ w,    // (16,3,3,3)
                   const float* __restrict__ cb,   // (16)
                   const float* __restrict__ bg,
                   const float* __restrict__ bb,
                   const float* __restrict__ bm,
                   const float* __restrict__ bv,
                   float* __restrict__ g1)
{
    __shared__ float simg[3*34*66];   // 3 ci x 34 rows x 66 cols (col-padded)
    __shared__ float sscale[16];
    __shared__ float sshift[16];
    const int im = blockIdx.x >> 1;
    const int h  = blockIdx.x & 1;    // half: pooled rows 16h..16h+15
    const int t  = threadIdx.x;

    // zero left/right pad columns (rows fully written by staging, incl. OOB zeros)
    if (t < 204) {                    // 3 ci * 34 rows * 2 cols
        int ci = t / 68;
        int r2 = t - ci*68;
        int ry = r2 >> 1;
        int col = (r2 & 1) ? 65 : 0;
        simg[ci*2244 + ry*66 + col] = 0.f;
    }
    if (t < 16) {
        float inv = bg[t] * rsqrtf(bv[t] + BN_EPS);
        sscale[t] = inv;
        sshift[t] = cb[t]*inv + bb[t] - bm[t]*inv;
    }

    // stage rows 32h-1 .. 32h+32 (34 rows); OOB rows written as zeros
    const float* xin = x + (size_t)im*12288;
    for (int i4 = t; i4 < 1632; i4 += 256) {   // 3*34*64/4
        int e   = i4 * 4;
        int ci  = e / 2176;           // 34*64
        int rem = e - ci*2176;
        int ry  = rem >> 6;
        int cx  = rem & 63;
        int g   = 32*h - 1 + ry;      // source row
        float4 vv = make_float4(0.f,0.f,0.f,0.f);
        if (g >= 0 && g < 64)
            vv = *reinterpret_cast<const float4*>(&xin[ci*4096 + g*64 + cx]);
        float* dst = &simg[ci*2244 + ry*66 + cx + 1];
        dst[0]=vv.x; dst[1]=vv.y; dst[2]=vv.z; dst[3]=vv.w;
    }
    __syncthreads();

    const int wv      = __builtin_amdgcn_readfirstlane(t >> 6);
    const int lane    = t & 63;
    const int co_base = (wv >> 1) * 8;     // waves 0,1 -> co 0..7 ; waves 2,3 -> co 8..15
    const int pos_base= (wv & 1) * 256;    // position half

    for (int step = 0; step < 4; ++step) {
        int pos = pos_base + step*64 + lane;   // 0..511 local pooled position
        int py = pos >> 5, px = pos & 31;      // local pooled row 0..15, col 0..31
        float acc[8][4];
        #pragma unroll
        for (int c = 0; c < 8; ++c) {
            acc[c][0]=0.f; acc[c][1]=0.f; acc[c][2]=0.f; acc[c][3]=0.f;
        }
        #pragma unroll
        for (int ci = 0; ci < 3; ++ci) {
            float p[16];
            const float* sp = &simg[ci*2244 + (2*py)*66 + 2*px];
            #pragma unroll
            for (int i = 0; i < 4; ++i) {
                const float2* sp2 = reinterpret_cast<const float2*>(sp + i*66);
                float2 a0 = sp2[0];
                float2 a1 = sp2[1];
                p[i*4+0]=a0.x; p[i*4+1]=a0.y; p[i*4+2]=a1.x; p[i*4+3]=a1.y;
            }
            #pragma unroll
            for (int c = 0; c < 8; ++c) {
                const float* wp = &w[(co_base + c)*27 + ci*9];  // wave-uniform -> s_load
                #pragma unroll
                for (int ky = 0; ky < 3; ++ky)
                    #pragma unroll
                    for (int kx = 0; kx < 3; ++kx) {
                        float wvv = wp[ky*3+kx];
                        acc[c][0] = fmaf(wvv, p[ ky   *4+kx  ], acc[c][0]);
                        acc[c][1] = fmaf(wvv, p[ ky   *4+kx+1], acc[c][1]);
                        acc[c][2] = fmaf(wvv, p[(ky+1)*4+kx  ], acc[c][2]);
                        acc[c][3] = fmaf(wvv, p[(ky+1)*4+kx+1], acc[c][3]);
                    }
            }
        }
        #pragma unroll
        for (int c = 0; c < 8; ++c) {
            int co = co_base + c;
            float sc = sscale[co], sh = sshift[co];
            float v0 = fmaf(acc[c][0], sc, sh);
            float v1 = fmaf(acc[c][1], sc, sh);
            float v2 = fmaf(acc[c][2], sc, sh);
            float v3 = fmaf(acc[c][3], sc, sh);
            float mx = fmaxf(fmaxf(v0,v1), fmaxf(v2,v3));
            g1[(((size_t)im*16 + co) << 10) + (16*h + py)*32 + px] = fmaxf(mx, 0.f);
        }
    }
}

// ---------------- Stage 2: conv2(16->32) + BN + ReLU + pool2 ----------------
// g1 (1024,16,32,32) -> g2 (1024,32,16,16)
__global__ __launch_bounds__(256)
void stage2_kernel(const float* __restrict__ g1,
                   const float* __restrict__ w,    // (32,16,3,3)
                   const float* __restrict__ cb,
                   const float* __restrict__ bg,
                   const float* __restrict__ bb,
                   const float* __restrict__ bm,
                   const float* __restrict__ bv,
                   float* __restrict__ g2)
{
    __shared__ float simg[16*34*34];  // 18496 floats, zero-padded
    __shared__ float sscale[32];
    __shared__ float sshift[32];
    const int b = blockIdx.x;
    const int t = threadIdx.x;

    for (int i = t; i < 16*34*34; i += 256) simg[i] = 0.f;
    if (t < 32) {
        float inv = bg[t] * rsqrtf(bv[t] + BN_EPS);
        sscale[t] = inv;
        sshift[t] = cb[t]*inv + bb[t] - bm[t]*inv;
    }
    __syncthreads();

    const float4* gin = reinterpret_cast<const float4*>(g1 + (size_t)b*16384);
    #pragma unroll
    for (int k = 0; k < 16; ++k) {
        int i4 = t + k*256;            // 0..4095
        float4 vv = gin[i4];
        int e  = i4*4;
        int ci = e >> 10;
        int rem = e & 1023;
        int y  = rem >> 5;
        int xx = rem & 31;
        float* dst = &simg[ci*1156 + (y+1)*34 + (xx+1)];
        dst[0]=vv.x; dst[1]=vv.y; dst[2]=vv.z; dst[3]=vv.w;
    }
    __syncthreads();

    const int gg   = __builtin_amdgcn_readfirstlane(t >> 6);  // wave -> co group
    const int lane = t & 63;

    for (int it = 0; it < 4; ++it) {
        int pos = it*64 + lane;        // pooled position 0..255
        int py = pos >> 4, px = pos & 15;
        float acc[8][4];
        #pragma unroll
        for (int c = 0; c < 8; ++c) {
            acc[c][0]=0.f; acc[c][1]=0.f; acc[c][2]=0.f; acc[c][3]=0.f;
        }
        for (int ci = 0; ci < 16; ++ci) {
            float p[16];
            const float* sp = &simg[ci*1156 + (2*py)*34 + 2*px];
            #pragma unroll
            for (int i = 0; i < 4; ++i)
                #pragma unroll
                for (int j = 0; j < 4; ++j)
                    p[i*4+j] = sp[i*34+j];
            #pragma unroll
            for (int c = 0; c < 8; ++c) {
                const float* wp = &w[((gg*8 + c)*16 + ci)*9];  // wave-uniform -> s_load
                #pragma unroll
                for (int ky = 0; ky < 3; ++ky)
                    #pragma unroll
                    for (int kx = 0; kx < 3; ++kx) {
                        float wv = wp[ky*3+kx];
                        acc[c][0] = fmaf(wv, p[ ky   *4+kx  ], acc[c][0]);
                        acc[c][1] = fmaf(wv, p[ ky   *4+kx+1], acc[c][1]);
                        acc[c][2] = fmaf(wv, p[(ky+1)*4+kx  ], acc[c][2]);
                        acc[c][3] = fmaf(wv, p[(ky+1)*4+kx+1], acc[c][3]);
                    }
            }
        }
        #pragma unroll
        for (int c = 0; c < 8; ++c) {
            int co = gg*8 + c;
            float sc = sscale[co], sh = sshift[co];
            float v0 = fmaf(acc[c][0], sc, sh);
            float v1 = fmaf(acc[c][1], sc, sh);
            float v2 = fmaf(acc[c][2], sc, sh);
            float v3 = fmaf(acc[c][3], sc, sh);
            float mx = fmaxf(fmaxf(v0,v1), fmaxf(v2,v3));
            g2[(((size_t)b*32 + co) << 8) + pos] = fmaxf(mx, 0.f);
        }
    }
}

// ------- Stage 3: conv3(32->64)+BN+ReLU+pool2 + proj + quantum + cls -------
// g2 (1024,32,16,16) -> out (1024,10)
__global__ __launch_bounds__(256)
void stage3_kernel(const float* __restrict__ g2,
                   const float* __restrict__ w,    // (64,32,3,3)
                   const float* __restrict__ cb,
                   const float* __restrict__ bg,
                   const float* __restrict__ bb,
                   const float* __restrict__ bm,
                   const float* __restrict__ bv,
                   const float* __restrict__ pw,   // (4,4096)
                   const float* __restrict__ pb,   // (4)
                   const float* __restrict__ cw,   // (10,10)
                   const float* __restrict__ cbias,// (10)
                   float* __restrict__ out)
{
    __shared__ float simg[32*18*18];  // 10368 floats, zero-padded
    __shared__ float fbuf[4096];      // flattened features (C,H,W)
    __shared__ float sscale[64];
    __shared__ float sshift[64];
    __shared__ float red[4][4];
    const int b = blockIdx.x;
    const int t = threadIdx.x;

    for (int i = t; i < 32*18*18; i += 256) simg[i] = 0.f;
    if (t < 64) {
        float inv = bg[t] * rsqrtf(bv[t] + BN_EPS);
        sscale[t] = inv;
        sshift[t] = cb[t]*inv + bb[t] - bm[t]*inv;
    }
    __syncthreads();

    const float4* gin = reinterpret_cast<const float4*>(g2 + (size_t)b*8192);
    #pragma unroll
    for (int k = 0; k < 8; ++k) {
        int i4 = t + k*256;            // 0..2047
        float4 vv = gin[i4];
        int e  = i4*4;
        int ci = e >> 8;
        int rem = e & 255;
        int y  = rem >> 4;
        int xx = rem & 15;
        float* dst = &simg[ci*324 + (y+1)*18 + (xx+1)];
        dst[0]=vv.x; dst[1]=vv.y; dst[2]=vv.z; dst[3]=vv.w;
    }
    __syncthreads();

    const int gg   = __builtin_amdgcn_readfirstlane(t >> 6);  // wave -> 16 co's
    const int lane = t & 63;
    {
        int py = lane >> 3, px = lane & 7;   // pooled 8x8
        float acc[16][4];
        #pragma unroll
        for (int c = 0; c < 16; ++c) {
            acc[c][0]=0.f; acc[c][1]=0.f; acc[c][2]=0.f; acc[c][3]=0.f;
        }
        for (int ci = 0; ci < 32; ++ci) {
            float p[16];
            const float* sp = &simg[ci*324 + (2*py)*18 + 2*px];
            #pragma unroll
            for (int i = 0; i < 4; ++i)
                #pragma unroll
                for (int j = 0; j < 4; ++j)
                    p[i*4+j] = sp[i*18+j];
            #pragma unroll
            for (int c = 0; c < 16; ++c) {
                const float* wp = &w[((gg*16 + c)*32 + ci)*9];  // wave-uniform
                #pragma unroll
                for (int ky = 0; ky < 3; ++ky)
                    #pragma unroll
                    for (int kx = 0; kx < 3; ++kx) {
                        float wv = wp[ky*3+kx];
                        acc[c][0] = fmaf(wv, p[ ky   *4+kx  ], acc[c][0]);
                        acc[c][1] = fmaf(wv, p[ ky   *4+kx+1], acc[c][1]);
                        acc[c][2] = fmaf(wv, p[(ky+1)*4+kx  ], acc[c][2]);
                        acc[c][3] = fmaf(wv, p[(ky+1)*4+kx+1], acc[c][3]);
                    }
            }
        }
        #pragma unroll
        for (int c = 0; c < 16; ++c) {
            int co = gg*16 + c;
            float sc = sscale[co], sh = sshift[co];
            float v0 = fmaf(acc[c][0], sc, sh);
            float v1 = fmaf(acc[c][1], sc, sh);
            float v2 = fmaf(acc[c][2], sc, sh);
            float v3 = fmaf(acc[c][3], sc, sh);
            float mx = fmaxf(fmaxf(v0,v1), fmaxf(v2,v3));
            fbuf[co*64 + lane] = fmaxf(mx, 0.f);
        }
    }
    __syncthreads();

    // projection z = f @ proj_w.T + proj_b   (4 outputs)
    float z0=0.f, z1=0.f, z2=0.f, z3=0.f;
    #pragma unroll
    for (int k = 0; k < 16; ++k) {
        int j = k*256 + t;
        float fv = fbuf[j];
        z0 = fmaf(fv, pw[        j], z0);
        z1 = fmaf(fv, pw[ 4096 + j], z1);
        z2 = fmaf(fv, pw[ 8192 + j], z2);
        z3 = fmaf(fv, pw[12288 + j], z3);
    }
    #pragma unroll
    for (int off = 32; off > 0; off >>= 1) {
        z0 += __shfl_down(z0, off);
        z1 += __shfl_down(z1, off);
        z2 += __shfl_down(z2, off);
        z3 += __shfl_down(z3, off);
    }
    if (lane == 0) { red[gg][0]=z0; red[gg][1]=z1; red[gg][2]=z2; red[gg][3]=z3; }
    __syncthreads();

    if (t == 0) {
        float z[4];
        #pragma unroll
        for (int p2 = 0; p2 < 4; ++p2)
            z[p2] = red[0][p2]+red[1][p2]+red[2][p2]+red[3][p2] + pb[p2];

        float qc[4], qs[4];
        #pragma unroll
        for (int k = 0; k < 4; ++k) {
            float h = 0.5f * ALPHA * z[k];
            qc[k] = cosf(h);
            qs[k] = sinf(h);
        }
        float st[16];
        #pragma unroll
        for (int j = 0; j < 16; ++j) {
            float v0 = ((j>>3)&1) ? qs[0] : qc[0];
            float v1 = ((j>>2)&1) ? qs[1] : qc[1];
            float v2 = ((j>>1)&1) ? qs[2] : qc[2];
            float v3 = ( j    &1) ? qs[3] : qc[3];
            st[j] = v0*v1*v2*v3;
        }
        // CNOT permutations (c,t) in (0,1),(1,2),(2,3),(3,0): state = state[perm]
        const int csrc[4] = {0,1,2,3};
        const int ctgt[4] = {1,2,3,0};
        #pragma unroll
        for (int pp = 0; pp < 4; ++pp) {
            float tmp[16];
            #pragma unroll
            for (int idx = 0; idx < 16; ++idx) {
                int bit = (idx >> (3 - csrc[pp])) & 1;
                int src = bit ? (idx ^ (1 << (3 - ctgt[pp]))) : idx;
                tmp[idx] = st[src];
            }
            #pragma unroll
            for (int idx = 0; idx < 16; ++idx) st[idx] = tmp[idx];
        }
        float feat[10];
        #pragma unroll
        for (int f = 0; f < 10; ++f) feat[f] = 0.f;
        #pragma unroll
        for (int j = 0; j < 16; ++j) {
            float pr = st[j]*st[j];
            float s0 = ((j>>3)&1) ? -1.f : 1.f;
            float s1 = ((j>>2)&1) ? -1.f : 1.f;
            float s2 = ((j>>1)&1) ? -1.f : 1.f;
            float s3 = ( j    &1) ? -1.f : 1.f;
            feat[0] += s0*pr;       feat[1] += s1*pr;
            feat[2] += s2*pr;       feat[3] += s3*pr;
            feat[4] += s0*s1*pr;    feat[5] += s0*s2*pr;
            feat[6] += s0*s3*pr;    feat[7] += s1*s2*pr;
            feat[8] += s1*s3*pr;    feat[9] += s2*s3*pr;
        }
        #pragma unroll
        for (int o = 0; o < 10; ++o) {
            float a = cbias[o];
            #pragma unroll
            for (int f = 0; f < 10; ++f) a = fmaf(feat[f], cw[o*10+f], a);
            out[(size_t)b*10 + o] = a;
        }
    }
}

extern "C" void kernel_launch(void* const* d_in, const int* in_sizes, int n_in,
                              void* d_out, int out_size, void* d_ws, size_t ws_size,
                              hipStream_t stream)
{
    const float* x   = (const float*)d_in[0];
    const float* c1w = (const float*)d_in[1];
    const float* c1b = (const float*)d_in[2];
    const float* c2w = (const float*)d_in[3];
    const float* c2b = (const float*)d_in[4];
    const float* c3w = (const float*)d_in[5];
    const float* c3b = (const float*)d_in[6];
    const float* b1g = (const float*)d_in[7];
    const float* b1b = (const float*)d_in[8];
    const float* b1m = (const float*)d_in[9];
    const float* b1v = (const float*)d_in[10];
    const float* b2g = (const float*)d_in[11];
    const float* b2b = (const float*)d_in[12];
    const float* b2m = (const float*)d_in[13];
    const float* b2v = (const float*)d_in[14];
    const float* b3g = (const float*)d_in[15];
    const float* b3b = (const float*)d_in[16];
    const float* b3m = (const float*)d_in[17];
    const float* b3v = (const float*)d_in[18];
    const float* pw  = (const float*)d_in[19];
    const float* pb  = (const float*)d_in[20];
    const float* cw  = (const float*)d_in[21];
    const float* cbv = (const float*)d_in[22];

    float* g1 = (float*)d_ws;                             // 1024*16*32*32 fp32 = 64 MB
    float* g2 = (float*)((char*)d_ws + (size_t)67108864); // 1024*32*16*16 fp32 = 32 MB
    float* out = (float*)d_out;

    stage1_kernel<<<2048, 256, 0, stream>>>(x,  c1w, c1b, b1g, b1b, b1m, b1v, g1);
    stage2_kernel<<<1024, 256, 0, stream>>>(g1, c2w, c2b, b2g, b2b, b2m, b2v, g2);
    stage3_kernel<<<1024, 256, 0, stream>>>(g2, c3w, c3b, b3g, b3b, b3m, b3v,
                                            pw, pb, cw, cbv, out);
}

// Round 5
// 424.586 us; speedup vs baseline: 1.3477x; 1.1314x over previous
//
#include <hip/hip_runtime.h>
#include <math.h>

#define ALPHA 1.57f
#define BN_EPS 1e-5f

// ---------------- Stage 1: conv1(3->16) + BN + ReLU + pool2 ----------------
// x (1024,3,64,64) -> g1 (1024,16,32,32)
// 2 blocks per image (half-image + halo), 8 co per wave, float2 LDS reads.
__global__ __launch_bounds__(256)
void stage1_kernel(const float* __restrict__ x,
                   const float* __restrict__ w,    // (16,3,3,3)
                   const float* __restrict__ cb,   // (16)
                   const float* __restrict__ bg,
                   const float* __restrict__ bb,
                   const float* __restrict__ bm,
                   const float* __restrict__ bv,
                   float* __restrict__ g1)
{
    __shared__ float simg[3*34*66];   // 3 ci x 34 rows x 66 cols (col-padded)
    __shared__ float sscale[16];
    __shared__ float sshift[16];
    const int im = blockIdx.x >> 1;
    const int h  = blockIdx.x & 1;    // half: pooled rows 16h..16h+15
    const int t  = threadIdx.x;

    if (t < 204) {                    // 3 ci * 34 rows * 2 cols
        int ci = t / 68;
        int r2 = t - ci*68;
        int ry = r2 >> 1;
        int col = (r2 & 1) ? 65 : 0;
        simg[ci*2244 + ry*66 + col] = 0.f;
    }
    if (t < 16) {
        float inv = bg[t] * rsqrtf(bv[t] + BN_EPS);
        sscale[t] = inv;
        sshift[t] = cb[t]*inv + bb[t] - bm[t]*inv;
    }

    const float* xin = x + (size_t)im*12288;
    for (int i4 = t; i4 < 1632; i4 += 256) {   // 3*34*64/4
        int e   = i4 * 4;
        int ci  = e / 2176;           // 34*64
        int rem = e - ci*2176;
        int ry  = rem >> 6;
        int cx  = rem & 63;
        int g   = 32*h - 1 + ry;      // source row
        float4 vv = make_float4(0.f,0.f,0.f,0.f);
        if (g >= 0 && g < 64)
            vv = *reinterpret_cast<const float4*>(&xin[ci*4096 + g*64 + cx]);
        float* dst = &simg[ci*2244 + ry*66 + cx + 1];
        dst[0]=vv.x; dst[1]=vv.y; dst[2]=vv.z; dst[3]=vv.w;
    }
    __syncthreads();

    const int wv      = __builtin_amdgcn_readfirstlane(t >> 6);
    const int lane    = t & 63;
    const int co_base = (wv >> 1) * 8;
    const int pos_base= (wv & 1) * 256;

    for (int step = 0; step < 4; ++step) {
        int pos = pos_base + step*64 + lane;
        int py = pos >> 5, px = pos & 31;
        float acc[8][4];
        #pragma unroll
        for (int c = 0; c < 8; ++c) {
            acc[c][0]=0.f; acc[c][1]=0.f; acc[c][2]=0.f; acc[c][3]=0.f;
        }
        #pragma unroll
        for (int ci = 0; ci < 3; ++ci) {
            float p[16];
            const float* sp = &simg[ci*2244 + (2*py)*66 + 2*px];
            #pragma unroll
            for (int i = 0; i < 4; ++i) {
                const float2* sp2 = reinterpret_cast<const float2*>(sp + i*66);
                float2 a0 = sp2[0];
                float2 a1 = sp2[1];
                p[i*4+0]=a0.x; p[i*4+1]=a0.y; p[i*4+2]=a1.x; p[i*4+3]=a1.y;
            }
            #pragma unroll
            for (int c = 0; c < 8; ++c) {
                const float* wp = &w[(co_base + c)*27 + ci*9];
                #pragma unroll
                for (int ky = 0; ky < 3; ++ky)
                    #pragma unroll
                    for (int kx = 0; kx < 3; ++kx) {
                        float wvv = wp[ky*3+kx];
                        acc[c][0] = fmaf(wvv, p[ ky   *4+kx  ], acc[c][0]);
                        acc[c][1] = fmaf(wvv, p[ ky   *4+kx+1], acc[c][1]);
                        acc[c][2] = fmaf(wvv, p[(ky+1)*4+kx  ], acc[c][2]);
                        acc[c][3] = fmaf(wvv, p[(ky+1)*4+kx+1], acc[c][3]);
                    }
            }
        }
        #pragma unroll
        for (int c = 0; c < 8; ++c) {
            int co = co_base + c;
            float sc = sscale[co], sh = sshift[co];
            float v0 = fmaf(acc[c][0], sc, sh);
            float v1 = fmaf(acc[c][1], sc, sh);
            float v2 = fmaf(acc[c][2], sc, sh);
            float v3 = fmaf(acc[c][3], sc, sh);
            float mx = fmaxf(fmaxf(v0,v1), fmaxf(v2,v3));
            g1[(((size_t)im*16 + co) << 10) + (16*h + py)*32 + px] = fmaxf(mx, 0.f);
        }
    }
}

// ---------------- Stage 2: conv2(16->32) + BN + ReLU + pool2 ----------------
// g1 (1024,16,32,32) -> g2 (1024,32,16,16)
// v2: 512 threads (8 waves: 4 co-groups x 2 position halves), float2 LDS reads.
__global__ __launch_bounds__(512)
void stage2_kernel(const float* __restrict__ g1,
                   const float* __restrict__ w,    // (32,16,3,3)
                   const float* __restrict__ cb,
                   const float* __restrict__ bg,
                   const float* __restrict__ bb,
                   const float* __restrict__ bm,
                   const float* __restrict__ bv,
                   float* __restrict__ g2)
{
    __shared__ float simg[16*34*34];  // 18496 floats, zero-padded
    __shared__ float sscale[32];
    __shared__ float sshift[32];
    const int b = blockIdx.x;
    const int t = threadIdx.x;

    for (int i = t; i < 16*34*34; i += 512) simg[i] = 0.f;
    if (t < 32) {
        float inv = bg[t] * rsqrtf(bv[t] + BN_EPS);
        sscale[t] = inv;
        sshift[t] = cb[t]*inv + bb[t] - bm[t]*inv;
    }
    __syncthreads();

    const float4* gin = reinterpret_cast<const float4*>(g1 + (size_t)b*16384);
    #pragma unroll
    for (int k = 0; k < 8; ++k) {
        int i4 = t + k*512;            // 0..4095
        float4 vv = gin[i4];
        int e  = i4*4;
        int ci = e >> 10;
        int rem = e & 1023;
        int y  = rem >> 5;
        int xx = rem & 31;
        float* dst = &simg[ci*1156 + (y+1)*34 + (xx+1)];
        dst[0]=vv.x; dst[1]=vv.y; dst[2]=vv.z; dst[3]=vv.w;
    }
    __syncthreads();

    const int wv      = __builtin_amdgcn_readfirstlane(t >> 6);  // 0..7
    const int lane    = t & 63;
    const int co_base = (wv >> 1) * 8;
    const int pos_base= (wv & 1) * 128;

    for (int step = 0; step < 2; ++step) {
        int pos = pos_base + step*64 + lane;   // 0..255
        int py = pos >> 4, px = pos & 15;
        float acc[8][4];
        #pragma unroll
        for (int c = 0; c < 8; ++c) {
            acc[c][0]=0.f; acc[c][1]=0.f; acc[c][2]=0.f; acc[c][3]=0.f;
        }
        for (int ci = 0; ci < 16; ++ci) {
            float p[16];
            const float* sp = &simg[ci*1156 + (2*py)*34 + 2*px];
            #pragma unroll
            for (int i = 0; i < 4; ++i) {
                const float2* sp2 = reinterpret_cast<const float2*>(sp + i*34);
                float2 a0 = sp2[0];
                float2 a1 = sp2[1];
                p[i*4+0]=a0.x; p[i*4+1]=a0.y; p[i*4+2]=a1.x; p[i*4+3]=a1.y;
            }
            #pragma unroll
            for (int c = 0; c < 8; ++c) {
                const float* wp = &w[((co_base + c)*16 + ci)*9];  // wave-uniform
                #pragma unroll
                for (int ky = 0; ky < 3; ++ky)
                    #pragma unroll
                    for (int kx = 0; kx < 3; ++kx) {
                        float wvv = wp[ky*3+kx];
                        acc[c][0] = fmaf(wvv, p[ ky   *4+kx  ], acc[c][0]);
                        acc[c][1] = fmaf(wvv, p[ ky   *4+kx+1], acc[c][1]);
                        acc[c][2] = fmaf(wvv, p[(ky+1)*4+kx  ], acc[c][2]);
                        acc[c][3] = fmaf(wvv, p[(ky+1)*4+kx+1], acc[c][3]);
                    }
            }
        }
        #pragma unroll
        for (int c = 0; c < 8; ++c) {
            int co = co_base + c;
            float sc = sscale[co], sh = sshift[co];
            float v0 = fmaf(acc[c][0], sc, sh);
            float v1 = fmaf(acc[c][1], sc, sh);
            float v2 = fmaf(acc[c][2], sc, sh);
            float v3 = fmaf(acc[c][3], sc, sh);
            float mx = fmaxf(fmaxf(v0,v1), fmaxf(v2,v3));
            g2[(((size_t)b*32 + co) << 8) + pos] = fmaxf(mx, 0.f);
        }
    }
}

// ------- Stage 3: conv3(32->64)+BN+ReLU+pool2 + proj + quantum + cls -------
// g2 (1024,32,16,16) -> out (1024,10)
// v2: 512 threads (8 waves x 8 co), float2 LDS reads, fbuf aliased over simg.
__global__ __launch_bounds__(512)
void stage3_kernel(const float* __restrict__ g2,
                   const float* __restrict__ w,    // (64,32,3,3)
                   const float* __restrict__ cb,
                   const float* __restrict__ bg,
                   const float* __restrict__ bb,
                   const float* __restrict__ bm,
                   const float* __restrict__ bv,
                   const float* __restrict__ pw,   // (4,4096)
                   const float* __restrict__ pb,   // (4)
                   const float* __restrict__ cw,   // (10,10)
                   const float* __restrict__ cbias,// (10)
                   float* __restrict__ out)
{
    __shared__ float simg[32*18*18];  // 10368 floats; fbuf aliases first 4096 after conv
    __shared__ float sscale[64];
    __shared__ float sshift[64];
    __shared__ float red[8][4];
    float* fbuf = simg;               // alias (simg dead after conv; barriers below)
    const int b = blockIdx.x;
    const int t = threadIdx.x;

    for (int i = t; i < 32*18*18; i += 512) simg[i] = 0.f;
    if (t < 64) {
        float inv = bg[t] * rsqrtf(bv[t] + BN_EPS);
        sscale[t] = inv;
        sshift[t] = cb[t]*inv + bb[t] - bm[t]*inv;
    }
    __syncthreads();

    const float4* gin = reinterpret_cast<const float4*>(g2 + (size_t)b*8192);
    #pragma unroll
    for (int k = 0; k < 4; ++k) {
        int i4 = t + k*512;            // 0..2047
        float4 vv = gin[i4];
        int e  = i4*4;
        int ci = e >> 8;
        int rem = e & 255;
        int y  = rem >> 4;
        int xx = rem & 15;
        float* dst = &simg[ci*324 + (y+1)*18 + (xx+1)];
        dst[0]=vv.x; dst[1]=vv.y; dst[2]=vv.z; dst[3]=vv.w;
    }
    __syncthreads();

    const int wv   = __builtin_amdgcn_readfirstlane(t >> 6);  // 0..7
    const int lane = t & 63;
    const int co_base = wv * 8;
    float res[8];                     // post BN+ReLU+pool results, held in regs
    {
        int py = lane >> 3, px = lane & 7;   // pooled 8x8
        float acc[8][4];
        #pragma unroll
        for (int c = 0; c < 8; ++c) {
            acc[c][0]=0.f; acc[c][1]=0.f; acc[c][2]=0.f; acc[c][3]=0.f;
        }
        for (int ci = 0; ci < 32; ++ci) {
            float p[16];
            const float* sp = &simg[ci*324 + (2*py)*18 + 2*px];
            #pragma unroll
            for (int i = 0; i < 4; ++i) {
                const float2* sp2 = reinterpret_cast<const float2*>(sp + i*18);
                float2 a0 = sp2[0];
                float2 a1 = sp2[1];
                p[i*4+0]=a0.x; p[i*4+1]=a0.y; p[i*4+2]=a1.x; p[i*4+3]=a1.y;
            }
            #pragma unroll
            for (int c = 0; c < 8; ++c) {
                const float* wp = &w[((co_base + c)*32 + ci)*9];  // wave-uniform
                #pragma unroll
                for (int ky = 0; ky < 3; ++ky)
                    #pragma unroll
                    for (int kx = 0; kx < 3; ++kx) {
                        float wvv = wp[ky*3+kx];
                        acc[c][0] = fmaf(wvv, p[ ky   *4+kx  ], acc[c][0]);
                        acc[c][1] = fmaf(wvv, p[ ky   *4+kx+1], acc[c][1]);
                        acc[c][2] = fmaf(wvv, p[(ky+1)*4+kx  ], acc[c][2]);
                        acc[c][3] = fmaf(wvv, p[(ky+1)*4+kx+1], acc[c][3]);
                    }
            }
        }
        #pragma unroll
        for (int c = 0; c < 8; ++c) {
            int co = co_base + c;
            float sc = sscale[co], sh = sshift[co];
            float v0 = fmaf(acc[c][0], sc, sh);
            float v1 = fmaf(acc[c][1], sc, sh);
            float v2 = fmaf(acc[c][2], sc, sh);
            float v3 = fmaf(acc[c][3], sc, sh);
            float mx = fmaxf(fmaxf(v0,v1), fmaxf(v2,v3));
            res[c] = fmaxf(mx, 0.f);
        }
    }
    __syncthreads();                  // all conv reads of simg done
    #pragma unroll
    for (int c = 0; c < 8; ++c)
        fbuf[(co_base + c)*64 + lane] = res[c];
    __syncthreads();                  // fbuf fully written

    // projection z = f @ proj_w.T + proj_b   (4 outputs)
    float z0=0.f, z1=0.f, z2=0.f, z3=0.f;
    #pragma unroll
    for (int k = 0; k < 8; ++k) {
        int j = k*512 + t;
        float fv = fbuf[j];
        z0 = fmaf(fv, pw[        j], z0);
        z1 = fmaf(fv, pw[ 4096 + j], z1);
        z2 = fmaf(fv, pw[ 8192 + j], z2);
        z3 = fmaf(fv, pw[12288 + j], z3);
    }
    #pragma unroll
    for (int off = 32; off > 0; off >>= 1) {
        z0 += __shfl_down(z0, off);
        z1 += __shfl_down(z1, off);
        z2 += __shfl_down(z2, off);
        z3 += __shfl_down(z3, off);
    }
    if (lane == 0) { red[wv][0]=z0; red[wv][1]=z1; red[wv][2]=z2; red[wv][3]=z3; }
    __syncthreads();

    if (t == 0) {
        float z[4];
        #pragma unroll
        for (int p2 = 0; p2 < 4; ++p2) {
            float s = pb[p2];
            #pragma unroll
            for (int r = 0; r < 8; ++r) s += red[r][p2];
            z[p2] = s;
        }

        float qc[4], qs[4];
        #pragma unroll
        for (int k = 0; k < 4; ++k) {
            float hh = 0.5f * ALPHA * z[k];
            qc[k] = cosf(hh);
            qs[k] = sinf(hh);
        }
        float st[16];
        #pragma unroll
        for (int j = 0; j < 16; ++j) {
            float v0 = ((j>>3)&1) ? qs[0] : qc[0];
            float v1 = ((j>>2)&1) ? qs[1] : qc[1];
            float v2 = ((j>>1)&1) ? qs[2] : qc[2];
            float v3 = ( j    &1) ? qs[3] : qc[3];
            st[j] = v0*v1*v2*v3;
        }
        const int csrc[4] = {0,1,2,3};
        const int ctgt[4] = {1,2,3,0};
        #pragma unroll
        for (int pp = 0; pp < 4; ++pp) {
            float tmp[16];
            #pragma unroll
            for (int idx = 0; idx < 16; ++idx) {
                int bit = (idx >> (3 - csrc[pp])) & 1;
                int src = bit ? (idx ^ (1 << (3 - ctgt[pp]))) : idx;
                tmp[idx] = st[src];
            }
            #pragma unroll
            for (int idx = 0; idx < 16; ++idx) st[idx] = tmp[idx];
        }
        float feat[10];
        #pragma unroll
        for (int f = 0; f < 10; ++f) feat[f] = 0.f;
        #pragma unroll
        for (int j = 0; j < 16; ++j) {
            float pr = st[j]*st[j];
            float s0 = ((j>>3)&1) ? -1.f : 1.f;
            float s1 = ((j>>2)&1) ? -1.f : 1.f;
            float s2 = ((j>>1)&1) ? -1.f : 1.f;
            float s3 = ( j    &1) ? -1.f : 1.f;
            feat[0] += s0*pr;       feat[1] += s1*pr;
            feat[2] += s2*pr;       feat[3] += s3*pr;
            feat[4] += s0*s1*pr;    feat[5] += s0*s2*pr;
            feat[6] += s0*s3*pr;    feat[7] += s1*s2*pr;
            feat[8] += s1*s3*pr;    feat[9] += s2*s3*pr;
        }
        #pragma unroll
        for (int o = 0; o < 10; ++o) {
            float a = cbias[o];
            #pragma unroll
            for (int f = 0; f < 10; ++f) a = fmaf(feat[f], cw[o*10+f], a);
            out[(size_t)b*10 + o] = a;
        }
    }
}

extern "C" void kernel_launch(void* const* d_in, const int* in_sizes, int n_in,
                              void* d_out, int out_size, void* d_ws, size_t ws_size,
                              hipStream_t stream)
{
    const float* x   = (const float*)d_in[0];
    const float* c1w = (const float*)d_in[1];
    const float* c1b = (const float*)d_in[2];
    const float* c2w = (const float*)d_in[3];
    const float* c2b = (const float*)d_in[4];
    const float* c3w = (const float*)d_in[5];
    const float* c3b = (const float*)d_in[6];
    const float* b1g = (const float*)d_in[7];
    const float* b1b = (const float*)d_in[8];
    const float* b1m = (const float*)d_in[9];
    const float* b1v = (const float*)d_in[10];
    const float* b2g = (const float*)d_in[11];
    const float* b2b = (const float*)d_in[12];
    const float* b2m = (const float*)d_in[13];
    const float* b2v = (const float*)d_in[14];
    const float* b3g = (const float*)d_in[15];
    const float* b3b = (const float*)d_in[16];
    const float* b3m = (const float*)d_in[17];
    const float* b3v = (const float*)d_in[18];
    const float* pw  = (const float*)d_in[19];
    const float* pb  = (const float*)d_in[20];
    const float* cw  = (const float*)d_in[21];
    const float* cbv = (const float*)d_in[22];

    float* g1 = (float*)d_ws;                             // 64 MB
    float* g2 = (float*)((char*)d_ws + (size_t)67108864); // 32 MB
    float* out = (float*)d_out;

    stage1_kernel<<<2048, 256, 0, stream>>>(x,  c1w, c1b, b1g, b1b, b1m, b1v, g1);
    stage2_kernel<<<1024, 512, 0, stream>>>(g1, c2w, c2b, b2g, b2b, b2m, b2v, g2);
    stage3_kernel<<<1024, 512, 0, stream>>>(g2, c3w, c3b, b3g, b3b, b3m, b3v,
                                            pw, pb, cw, cbv, out);
}

// Round 6
// 397.184 us; speedup vs baseline: 1.4407x; 1.0690x over previous
//
#include <hip/hip_runtime.h>
#include <math.h>

#define ALPHA 1.57f
#define BN_EPS 1e-5f

typedef __attribute__((ext_vector_type(8))) short short8v;
typedef __attribute__((ext_vector_type(4))) float f32x4;
typedef unsigned int uint32;
typedef unsigned short ushort16;

__device__ __forceinline__ ushort16 f2bf_rne(float f) {
    uint32 u = __float_as_uint(f);
    u += 0x7FFFu + ((u >> 16) & 1u);
    return (ushort16)(u >> 16);
}
__device__ __forceinline__ float bf2f(ushort16 h) {
    return __uint_as_float(((uint32)h) << 16);
}
// pack fp32 -> bf16 hi (low half) | bf16 lo (high half)
__device__ __forceinline__ uint32 packsplit(float f) {
    ushort16 hi = f2bf_rne(f);
    float r = f - bf2f(hi);
    ushort16 lo = f2bf_rne(r);
    return (uint32)hi | ((uint32)lo << 16);
}

// ---------------- Stage 1: conv1(3->16) + BN + ReLU + pool2 ----------------
// x (1024,3,64,64) -> g1 (1024,16,32,32)   [unchanged control]
__global__ __launch_bounds__(256)
void stage1_kernel(const float* __restrict__ x,
                   const float* __restrict__ w,
                   const float* __restrict__ cb,
                   const float* __restrict__ bg,
                   const float* __restrict__ bb,
                   const float* __restrict__ bm,
                   const float* __restrict__ bv,
                   float* __restrict__ g1)
{
    __shared__ float simg[3*34*66];
    __shared__ float sscale[16];
    __shared__ float sshift[16];
    const int im = blockIdx.x >> 1;
    const int h  = blockIdx.x & 1;
    const int t  = threadIdx.x;

    if (t < 204) {
        int ci = t / 68;
        int r2 = t - ci*68;
        int ry = r2 >> 1;
        int col = (r2 & 1) ? 65 : 0;
        simg[ci*2244 + ry*66 + col] = 0.f;
    }
    if (t < 16) {
        float inv = bg[t] * rsqrtf(bv[t] + BN_EPS);
        sscale[t] = inv;
        sshift[t] = cb[t]*inv + bb[t] - bm[t]*inv;
    }

    const float* xin = x + (size_t)im*12288;
    for (int i4 = t; i4 < 1632; i4 += 256) {
        int e   = i4 * 4;
        int ci  = e / 2176;
        int rem = e - ci*2176;
        int ry  = rem >> 6;
        int cx  = rem & 63;
        int g   = 32*h - 1 + ry;
        float4 vv = make_float4(0.f,0.f,0.f,0.f);
        if (g >= 0 && g < 64)
            vv = *reinterpret_cast<const float4*>(&xin[ci*4096 + g*64 + cx]);
        float* dst = &simg[ci*2244 + ry*66 + cx + 1];
        dst[0]=vv.x; dst[1]=vv.y; dst[2]=vv.z; dst[3]=vv.w;
    }
    __syncthreads();

    const int wv      = __builtin_amdgcn_readfirstlane(t >> 6);
    const int lane    = t & 63;
    const int co_base = (wv >> 1) * 8;
    const int pos_base= (wv & 1) * 256;

    for (int step = 0; step < 4; ++step) {
        int pos = pos_base + step*64 + lane;
        int py = pos >> 5, px = pos & 31;
        float acc[8][4];
        #pragma unroll
        for (int c = 0; c < 8; ++c) {
            acc[c][0]=0.f; acc[c][1]=0.f; acc[c][2]=0.f; acc[c][3]=0.f;
        }
        #pragma unroll
        for (int ci = 0; ci < 3; ++ci) {
            float p[16];
            const float* sp = &simg[ci*2244 + (2*py)*66 + 2*px];
            #pragma unroll
            for (int i = 0; i < 4; ++i) {
                const float2* sp2 = reinterpret_cast<const float2*>(sp + i*66);
                float2 a0 = sp2[0];
                float2 a1 = sp2[1];
                p[i*4+0]=a0.x; p[i*4+1]=a0.y; p[i*4+2]=a1.x; p[i*4+3]=a1.y;
            }
            #pragma unroll
            for (int c = 0; c < 8; ++c) {
                const float* wp = &w[(co_base + c)*27 + ci*9];
                #pragma unroll
                for (int ky = 0; ky < 3; ++ky)
                    #pragma unroll
                    for (int kx = 0; kx < 3; ++kx) {
                        float wvv = wp[ky*3+kx];
                        acc[c][0] = fmaf(wvv, p[ ky   *4+kx  ], acc[c][0]);
                        acc[c][1] = fmaf(wvv, p[ ky   *4+kx+1], acc[c][1]);
                        acc[c][2] = fmaf(wvv, p[(ky+1)*4+kx  ], acc[c][2]);
                        acc[c][3] = fmaf(wvv, p[(ky+1)*4+kx+1], acc[c][3]);
                    }
            }
        }
        #pragma unroll
        for (int c = 0; c < 8; ++c) {
            int co = co_base + c;
            float sc = sscale[co], sh = sshift[co];
            float v0 = fmaf(acc[c][0], sc, sh);
            float v1 = fmaf(acc[c][1], sc, sh);
            float v2 = fmaf(acc[c][2], sc, sh);
            float v3 = fmaf(acc[c][3], sc, sh);
            float mx = fmaxf(fmaxf(v0,v1), fmaxf(v2,v3));
            g1[(((size_t)im*16 + co) << 10) + (16*h + py)*32 + px] = fmaxf(mx, 0.f);
        }
    }
}

// ---------------- Stage 2: conv2(16->32) via MFMA implicit GEMM ----------------
// g1 (1024,16,32,32) -> g2 (1024,32,16,16)
// 2 blocks/image (16 local oy rows + halo). GEMM: C[32co][16x32pos], K=144 pad 160.
// Split-bf16 x3 for precision. img LDS packed hi|lo<<16.
__global__ __launch_bounds__(512)
void stage2_kernel(const float* __restrict__ g1,
                   const float* __restrict__ w,    // (32,16,3,3) = (32,144)
                   const float* __restrict__ cb,
                   const float* __restrict__ bg,
                   const float* __restrict__ bb,
                   const float* __restrict__ bm,
                   const float* __restrict__ bv,
                   float* __restrict__ g2)
{
    __shared__ uint32 img[16*18*34];  // 9792: ci x row(18) x col(34, padded)
    __shared__ float sscale[32];
    __shared__ float sshift[32];
    const int im = blockIdx.x >> 1;
    const int h  = blockIdx.x & 1;    // output rows 16h..16h+15
    const int t  = threadIdx.x;

    for (int i = t; i < 16*18*34; i += 512) img[i] = 0u;
    if (t < 32) {
        float inv = bg[t] * rsqrtf(bv[t] + BN_EPS);
        sscale[t] = inv;
        sshift[t] = cb[t]*inv + bb[t] - bm[t]*inv;
    }
    __syncthreads();

    // stage rows 16h-1 .. 16h+16 (18 rows), convert to split-bf16 pack
    const float* gin = g1 + (size_t)im*16384;
    for (int i4 = t; i4 < 2304; i4 += 512) {   // 16ci*18r*32x / 4
        int e   = i4 * 4;
        int ci  = ((e >> 6)*57) >> 9;          // e/576
        int rem = e - ci*576;
        int r   = rem >> 5;
        int xx  = rem & 31;
        int gy  = 16*h - 1 + r;
        float4 vv = make_float4(0.f,0.f,0.f,0.f);
        if (gy >= 0 && gy < 32)
            vv = *reinterpret_cast<const float4*>(&gin[ci*1024 + gy*32 + xx]);
        uint32* dst = &img[ci*612 + r*34 + xx + 1];
        dst[0]=packsplit(vv.x); dst[1]=packsplit(vv.y);
        dst[2]=packsplit(vv.z); dst[3]=packsplit(vv.w);
    }
    __syncthreads();

    const int wv   = __builtin_amdgcn_readfirstlane(t >> 6);  // 0..7 -> oy pair
    const int lane = t & 63;
    const int lg   = lane >> 4;       // k-group
    const int col  = lane & 15;       // N / row index within tile

    f32x4 acc[2][2][2];               // [ct][ntoy][oxh]
    #pragma unroll
    for (int a0 = 0; a0 < 2; ++a0)
        #pragma unroll
        for (int a1 = 0; a1 < 2; ++a1)
            #pragma unroll
            for (int a2 = 0; a2 < 2; ++a2)
                acc[a0][a1][a2] = (f32x4){0.f,0.f,0.f,0.f};

    #pragma unroll
    for (int g = 0; g < 5; ++g) {
        // A fragments: W[row=ct*16+col][k=32g+8lg+j], zero for k>=144
        short8v whi[2], wlo[2];
        #pragma unroll
        for (int ct = 0; ct < 2; ++ct) {
            int kbase = 32*g + 8*lg;
            bool valid = (g < 4) || (lg < 2);
            float wval[8];
            if (valid) {
                const float* wp = w + (ct*16 + col)*144 + kbase;
                float4 wa = *reinterpret_cast<const float4*>(wp);
                float4 wb2 = *reinterpret_cast<const float4*>(wp + 4);
                wval[0]=wa.x; wval[1]=wa.y; wval[2]=wa.z; wval[3]=wa.w;
                wval[4]=wb2.x; wval[5]=wb2.y; wval[6]=wb2.z; wval[7]=wb2.w;
            } else {
                #pragma unroll
                for (int j = 0; j < 8; ++j) wval[j] = 0.f;
            }
            #pragma unroll
            for (int j = 0; j < 8; ++j) {
                ushort16 hi = f2bf_rne(wval[j]);
                float r = wval[j] - bf2f(hi);
                whi[ct][j] = (short)hi;
                wlo[ct][j] = (short)f2bf_rne(r);
            }
        }
        // patch offsets for this k-chunk (depends on lg)
        int off[8];
        #pragma unroll
        for (int j = 0; j < 8; ++j) {
            int k = 32*g + 8*lg + j;
            int kc = (k < 144) ? k : 0;
            int ci = (kc*57) >> 9;
            int tap = kc - ci*9;
            int ky = (tap*11) >> 5;
            int kx = tap - 3*ky;
            off[j] = ci*612 + ky*34 + kx;
        }
        #pragma unroll
        for (int ntoy = 0; ntoy < 2; ++ntoy) {
            #pragma unroll
            for (int oxh = 0; oxh < 2; ++oxh) {
                int basev = (2*wv + ntoy)*34 + oxh*16 + col;
                short8v ph, pl;
                #pragma unroll
                for (int j = 0; j < 8; ++j) {
                    uint32 v = img[off[j] + basev];
                    ph[j] = (short)(v & 0xFFFFu);
                    pl[j] = (short)(v >> 16);
                }
                #pragma unroll
                for (int ct = 0; ct < 2; ++ct) {
                    acc[ct][ntoy][oxh] = __builtin_amdgcn_mfma_f32_16x16x32_bf16(
                        whi[ct], ph, acc[ct][ntoy][oxh], 0, 0, 0);
                    acc[ct][ntoy][oxh] = __builtin_amdgcn_mfma_f32_16x16x32_bf16(
                        whi[ct], pl, acc[ct][ntoy][oxh], 0, 0, 0);
                    acc[ct][ntoy][oxh] = __builtin_amdgcn_mfma_f32_16x16x32_bf16(
                        wlo[ct], ph, acc[ct][ntoy][oxh], 0, 0, 0);
                }
            }
        }
    }

    // epilogue: BN -> pool(2x2) -> ReLU -> store
    #pragma unroll
    for (int ct = 0; ct < 2; ++ct) {
        #pragma unroll
        for (int oxh = 0; oxh < 2; ++oxh) {
            #pragma unroll
            for (int r = 0; r < 4; ++r) {
                int co = ct*16 + 4*lg + r;
                float sc = sscale[co], sh = sshift[co];
                float v0 = fmaf(acc[ct][0][oxh][r], sc, sh);
                float v1 = fmaf(acc[ct][1][oxh][r], sc, sh);
                float m = fmaxf(v0, v1);
                float o = __shfl_xor(m, 1);
                m = fmaxf(fmaxf(m, o), 0.f);
                if (!(col & 1)) {
                    int px = oxh*8 + (col >> 1);
                    g2[(((size_t)im*32 + co) << 8) + (8*h + wv)*16 + px] = m;
                }
            }
        }
    }
}

// ------- Stage 3: conv3(32->64) via MFMA + BN/ReLU/pool + proj + quantum + cls -------
// g2 (1024,32,16,16) -> out (1024,10).  1 block/image, 8 waves.
// GEMM: C[64co][256pos], K=288 = 9 chunks of 32.
__global__ __launch_bounds__(512)
void stage3_kernel(const float* __restrict__ g2,
                   const float* __restrict__ w,    // (64,32,3,3) = (64,288)
                   const float* __restrict__ cb,
                   const float* __restrict__ bg,
                   const float* __restrict__ bb,
                   const float* __restrict__ bm,
                   const float* __restrict__ bv,
                   const float* __restrict__ pw,   // (4,4096)
                   const float* __restrict__ pb,   // (4)
                   const float* __restrict__ cw,   // (10,10)
                   const float* __restrict__ cbias,// (10)
                   float* __restrict__ out)
{
    __shared__ uint32 img[32*18*18];  // 10368; fbuf (4096 fp32 = 16KB) aliases after conv
    __shared__ float sscale[64];
    __shared__ float sshift[64];
    __shared__ float red[8][4];
    float* fbuf = (float*)img;
    const int b = blockIdx.x;
    const int t = threadIdx.x;

    for (int i = t; i < 32*18*18; i += 512) img[i] = 0u;
    if (t < 64) {
        float inv = bg[t] * rsqrtf(bv[t] + BN_EPS);
        sscale[t] = inv;
        sshift[t] = cb[t]*inv + bb[t] - bm[t]*inv;
    }
    __syncthreads();

    const float* gin = g2 + (size_t)b*8192;
    #pragma unroll
    for (int k = 0; k < 4; ++k) {
        int i4 = t + k*512;            // 0..2047
        int e  = i4*4;
        float4 vv = *reinterpret_cast<const float4*>(&gin[e]);
        int ci = e >> 8;
        int rem = e & 255;
        int y  = rem >> 4;
        int xx = rem & 15;
        uint32* dst = &img[ci*324 + (y+1)*18 + (xx+1)];
        dst[0]=packsplit(vv.x); dst[1]=packsplit(vv.y);
        dst[2]=packsplit(vv.z); dst[3]=packsplit(vv.w);
    }
    __syncthreads();

    const int wv   = __builtin_amdgcn_readfirstlane(t >> 6);  // 0..7 -> oy pair 2wv,2wv+1
    const int lane = t & 63;
    const int lg   = lane >> 4;
    const int col  = lane & 15;

    f32x4 acc[4][2];                  // [ct][ntoy]
    #pragma unroll
    for (int a0 = 0; a0 < 4; ++a0) {
        acc[a0][0] = (f32x4){0.f,0.f,0.f,0.f};
        acc[a0][1] = (f32x4){0.f,0.f,0.f,0.f};
    }

    #pragma unroll
    for (int g = 0; g < 9; ++g) {
        short8v whi[4], wlo[4];
        #pragma unroll
        for (int ct = 0; ct < 4; ++ct) {
            const float* wp = w + (ct*16 + col)*288 + 32*g + 8*lg;
            float4 wa = *reinterpret_cast<const float4*>(wp);
            float4 wb2 = *reinterpret_cast<const float4*>(wp + 4);
            float wval[8];
            wval[0]=wa.x; wval[1]=wa.y; wval[2]=wa.z; wval[3]=wa.w;
            wval[4]=wb2.x; wval[5]=wb2.y; wval[6]=wb2.z; wval[7]=wb2.w;
            #pragma unroll
            for (int j = 0; j < 8; ++j) {
                ushort16 hi = f2bf_rne(wval[j]);
                float r = wval[j] - bf2f(hi);
                whi[ct][j] = (short)hi;
                wlo[ct][j] = (short)f2bf_rne(r);
            }
        }
        int off[8];
        #pragma unroll
        for (int j = 0; j < 8; ++j) {
            int k = 32*g + 8*lg + j;
            int ci = (k*57) >> 9;
            int tap = k - ci*9;
            int ky = (tap*11) >> 5;
            int kx = tap - 3*ky;
            off[j] = ci*324 + ky*18 + kx;
        }
        #pragma unroll
        for (int ntoy = 0; ntoy < 2; ++ntoy) {
            int basev = (2*wv + ntoy)*18 + col;
            short8v ph, pl;
            #pragma unroll
            for (int j = 0; j < 8; ++j) {
                uint32 v = img[off[j] + basev];
                ph[j] = (short)(v & 0xFFFFu);
                pl[j] = (short)(v >> 16);
            }
            #pragma unroll
            for (int ct = 0; ct < 4; ++ct) {
                acc[ct][ntoy] = __builtin_amdgcn_mfma_f32_16x16x32_bf16(
                    whi[ct], ph, acc[ct][ntoy], 0, 0, 0);
                acc[ct][ntoy] = __builtin_amdgcn_mfma_f32_16x16x32_bf16(
                    whi[ct], pl, acc[ct][ntoy], 0, 0, 0);
                acc[ct][ntoy] = __builtin_amdgcn_mfma_f32_16x16x32_bf16(
                    wlo[ct], ph, acc[ct][ntoy], 0, 0, 0);
            }
        }
    }
    __syncthreads();                  // all img reads done; fbuf may overwrite

    #pragma unroll
    for (int ct = 0; ct < 4; ++ct) {
        #pragma unroll
        for (int r = 0; r < 4; ++r) {
            int co = ct*16 + 4*lg + r;
            float sc = sscale[co], sh = sshift[co];
            float v0 = fmaf(acc[ct][0][r], sc, sh);
            float v1 = fmaf(acc[ct][1][r], sc, sh);
            float m = fmaxf(v0, v1);
            float o = __shfl_xor(m, 1);
            m = fmaxf(fmaxf(m, o), 0.f);
            if (!(col & 1))
                fbuf[co*64 + wv*8 + (col >> 1)] = m;
        }
    }
    __syncthreads();

    // projection z = f @ proj_w.T + proj_b
    float z0=0.f, z1=0.f, z2=0.f, z3=0.f;
    #pragma unroll
    for (int k = 0; k < 8; ++k) {
        int j = k*512 + t;
        float fv = fbuf[j];
        z0 = fmaf(fv, pw[        j], z0);
        z1 = fmaf(fv, pw[ 4096 + j], z1);
        z2 = fmaf(fv, pw[ 8192 + j], z2);
        z3 = fmaf(fv, pw[12288 + j], z3);
    }
    #pragma unroll
    for (int off2 = 32; off2 > 0; off2 >>= 1) {
        z0 += __shfl_down(z0, off2);
        z1 += __shfl_down(z1, off2);
        z2 += __shfl_down(z2, off2);
        z3 += __shfl_down(z3, off2);
    }
    if (lane == 0) { red[wv][0]=z0; red[wv][1]=z1; red[wv][2]=z2; red[wv][3]=z3; }
    __syncthreads();

    if (t == 0) {
        float z[4];
        #pragma unroll
        for (int p2 = 0; p2 < 4; ++p2) {
            float s = pb[p2];
            #pragma unroll
            for (int r = 0; r < 8; ++r) s += red[r][p2];
            z[p2] = s;
        }
        float qc[4], qs[4];
        #pragma unroll
        for (int k = 0; k < 4; ++k) {
            float hh = 0.5f * ALPHA * z[k];
            qc[k] = cosf(hh);
            qs[k] = sinf(hh);
        }
        float st[16];
        #pragma unroll
        for (int j = 0; j < 16; ++j) {
            float v0 = ((j>>3)&1) ? qs[0] : qc[0];
            float v1 = ((j>>2)&1) ? qs[1] : qc[1];
            float v2 = ((j>>1)&1) ? qs[2] : qc[2];
            float v3 = ( j    &1) ? qs[3] : qc[3];
            st[j] = v0*v1*v2*v3;
        }
        const int csrc[4] = {0,1,2,3};
        const int ctgt[4] = {1,2,3,0};
        #pragma unroll
        for (int pp = 0; pp < 4; ++pp) {
            float tmp[16];
            #pragma unroll
            for (int idx = 0; idx < 16; ++idx) {
                int bit = (idx >> (3 - csrc[pp])) & 1;
                int src = bit ? (idx ^ (1 << (3 - ctgt[pp]))) : idx;
                tmp[idx] = st[src];
            }
            #pragma unroll
            for (int idx = 0; idx < 16; ++idx) st[idx] = tmp[idx];
        }
        float feat[10];
        #pragma unroll
        for (int f = 0; f < 10; ++f) feat[f] = 0.f;
        #pragma unroll
        for (int j = 0; j < 16; ++j) {
            float pr = st[j]*st[j];
            float s0 = ((j>>3)&1) ? -1.f : 1.f;
            float s1 = ((j>>2)&1) ? -1.f : 1.f;
            float s2 = ((j>>1)&1) ? -1.f : 1.f;
            float s3 = ( j    &1) ? -1.f : 1.f;
            feat[0] += s0*pr;       feat[1] += s1*pr;
            feat[2] += s2*pr;       feat[3] += s3*pr;
            feat[4] += s0*s1*pr;    feat[5] += s0*s2*pr;
            feat[6] += s0*s3*pr;    feat[7] += s1*s2*pr;
            feat[8] += s1*s3*pr;    feat[9] += s2*s3*pr;
        }
        #pragma unroll
        for (int o = 0; o < 10; ++o) {
            float a = cbias[o];
            #pragma unroll
            for (int f = 0; f < 10; ++f) a = fmaf(feat[f], cw[o*10+f], a);
            out[(size_t)b*10 + o] = a;
        }
    }
}

extern "C" void kernel_launch(void* const* d_in, const int* in_sizes, int n_in,
                              void* d_out, int out_size, void* d_ws, size_t ws_size,
                              hipStream_t stream)
{
    const float* x   = (const float*)d_in[0];
    const float* c1w = (const float*)d_in[1];
    const float* c1b = (const float*)d_in[2];
    const float* c2w = (const float*)d_in[3];
    const float* c2b = (const float*)d_in[4];
    const float* c3w = (const float*)d_in[5];
    const float* c3b = (const float*)d_in[6];
    const float* b1g = (const float*)d_in[7];
    const float* b1b = (const float*)d_in[8];
    const float* b1m = (const float*)d_in[9];
    const float* b1v = (const float*)d_in[10];
    const float* b2g = (const float*)d_in[11];
    const float* b2b = (const float*)d_in[12];
    const float* b2m = (const float*)d_in[13];
    const float* b2v = (const float*)d_in[14];
    const float* b3g = (const float*)d_in[15];
    const float* b3b = (const float*)d_in[16];
    const float* b3m = (const float*)d_in[17];
    const float* b3v = (const float*)d_in[18];
    const float* pw  = (const float*)d_in[19];
    const float* pb  = (const float*)d_in[20];
    const float* cw  = (const float*)d_in[21];
    const float* cbv = (const float*)d_in[22];

    float* g1 = (float*)d_ws;                             // 64 MB
    float* g2 = (float*)((char*)d_ws + (size_t)67108864); // 32 MB
    float* out = (float*)d_out;

    stage1_kernel<<<2048, 256, 0, stream>>>(x,  c1w, c1b, b1g, b1b, b1m, b1v, g1);
    stage2_kernel<<<2048, 512, 0, stream>>>(g1, c2w, c2b, b2g, b2b, b2m, b2v, g2);
    stage3_kernel<<<1024, 512, 0, stream>>>(g2, c3w, c3b, b3g, b3b, b3m, b3v,
                                            pw, pb, cw, cbv, out);
}

// Round 7
// 307.157 us; speedup vs baseline: 1.8629x; 1.2931x over previous
//
#include <hip/hip_runtime.h>
#include <math.h>

#define ALPHA 1.57f
#define BN_EPS 1e-5f

typedef __attribute__((ext_vector_type(8))) short short8v;
typedef __attribute__((ext_vector_type(4))) float f32x4;
typedef unsigned int uint32;
typedef unsigned short u16;

__device__ __forceinline__ u16 f2bf_rne(float f) {
    uint32 u = __float_as_uint(f);
    u += 0x7FFFu + ((u >> 16) & 1u);
    return (u16)(u >> 16);
}
__device__ __forceinline__ float bf2f(u16 h) {
    return __uint_as_float(((uint32)h) << 16);
}

// ---------------- Prep: split-bf16 weight fragments (once per call) ----------------
// w2 frags: k = tap*16+ci (K=144 pad 160): [g5][lg4][ct2][col16][j8]  -> 5120 shorts each
// w3 frags: k = tap*32+ci (K=288 exact):  [g9][lg4][ct4][col16][j8]  -> 18432 shorts each
__global__ __launch_bounds__(256)
void prep_kernel(const float* __restrict__ w2, const float* __restrict__ w3,
                 u16* __restrict__ w2hi, u16* __restrict__ w2lo,
                 u16* __restrict__ w3hi, u16* __restrict__ w3lo)
{
    int t = blockIdx.x*256 + threadIdx.x;
    if (t < 5120) {
        int j = t & 7, col = (t>>3)&15, ct = (t>>7)&1, lg = (t>>8)&3, g = t>>10;
        int k = 32*g + 8*lg + j;
        int tap = k >> 4, ci = k & 15;
        float v = (tap < 9) ? w2[(ct*16+col)*144 + ci*9 + tap] : 0.f;
        u16 hi = f2bf_rne(v);
        w2hi[t] = hi;
        w2lo[t] = f2bf_rne(v - bf2f(hi));
    }
    if (t < 18432) {
        int j = t & 7, col = (t>>3)&15, ct = (t>>7)&3, lg = (t>>9)&3, g = t>>11;
        int ci = 8*lg + j;                 // tap = g
        float v = w3[(ct*16+col)*288 + ci*9 + g];
        u16 hi = f2bf_rne(v);
        w3hi[t] = hi;
        w3lo[t] = f2bf_rne(v - bf2f(hi));
    }
}

// ---------------- Stage 1: conv1(3->16) + BN + ReLU + pool2 (fp32, control) ----------------
__global__ __launch_bounds__(256)
void stage1_kernel(const float* __restrict__ x,
                   const float* __restrict__ w,
                   const float* __restrict__ cb,
                   const float* __restrict__ bg,
                   const float* __restrict__ bb,
                   const float* __restrict__ bm,
                   const float* __restrict__ bv,
                   float* __restrict__ g1)
{
    __shared__ float simg[3*34*66];
    __shared__ float sscale[16];
    __shared__ float sshift[16];
    const int im = blockIdx.x >> 1;
    const int h  = blockIdx.x & 1;
    const int t  = threadIdx.x;

    if (t < 204) {
        int ci = t / 68;
        int r2 = t - ci*68;
        int ry = r2 >> 1;
        int col = (r2 & 1) ? 65 : 0;
        simg[ci*2244 + ry*66 + col] = 0.f;
    }
    if (t < 16) {
        float inv = bg[t] * rsqrtf(bv[t] + BN_EPS);
        sscale[t] = inv;
        sshift[t] = cb[t]*inv + bb[t] - bm[t]*inv;
    }

    const float* xin = x + (size_t)im*12288;
    for (int i4 = t; i4 < 1632; i4 += 256) {
        int e   = i4 * 4;
        int ci  = e / 2176;
        int rem = e - ci*2176;
        int ry  = rem >> 6;
        int cx  = rem & 63;
        int g   = 32*h - 1 + ry;
        float4 vv = make_float4(0.f,0.f,0.f,0.f);
        if (g >= 0 && g < 64)
            vv = *reinterpret_cast<const float4*>(&xin[ci*4096 + g*64 + cx]);
        float* dst = &simg[ci*2244 + ry*66 + cx + 1];
        dst[0]=vv.x; dst[1]=vv.y; dst[2]=vv.z; dst[3]=vv.w;
    }
    __syncthreads();

    const int wv      = __builtin_amdgcn_readfirstlane(t >> 6);
    const int lane    = t & 63;
    const int co_base = (wv >> 1) * 8;
    const int pos_base= (wv & 1) * 256;

    for (int step = 0; step < 4; ++step) {
        int pos = pos_base + step*64 + lane;
        int py = pos >> 5, px = pos & 31;
        float acc[8][4];
        #pragma unroll
        for (int c = 0; c < 8; ++c) {
            acc[c][0]=0.f; acc[c][1]=0.f; acc[c][2]=0.f; acc[c][3]=0.f;
        }
        #pragma unroll
        for (int ci = 0; ci < 3; ++ci) {
            float p[16];
            const float* sp = &simg[ci*2244 + (2*py)*66 + 2*px];
            #pragma unroll
            for (int i = 0; i < 4; ++i) {
                const float2* sp2 = reinterpret_cast<const float2*>(sp + i*66);
                float2 a0 = sp2[0];
                float2 a1 = sp2[1];
                p[i*4+0]=a0.x; p[i*4+1]=a0.y; p[i*4+2]=a1.x; p[i*4+3]=a1.y;
            }
            #pragma unroll
            for (int c = 0; c < 8; ++c) {
                const float* wp = &w[(co_base + c)*27 + ci*9];
                #pragma unroll
                for (int ky = 0; ky < 3; ++ky)
                    #pragma unroll
                    for (int kx = 0; kx < 3; ++kx) {
                        float wvv = wp[ky*3+kx];
                        acc[c][0] = fmaf(wvv, p[ ky   *4+kx  ], acc[c][0]);
                        acc[c][1] = fmaf(wvv, p[ ky   *4+kx+1], acc[c][1]);
                        acc[c][2] = fmaf(wvv, p[(ky+1)*4+kx  ], acc[c][2]);
                        acc[c][3] = fmaf(wvv, p[(ky+1)*4+kx+1], acc[c][3]);
                    }
            }
        }
        #pragma unroll
        for (int c = 0; c < 8; ++c) {
            int co = co_base + c;
            float sc = sscale[co], sh = sshift[co];
            float v0 = fmaf(acc[c][0], sc, sh);
            float v1 = fmaf(acc[c][1], sc, sh);
            float v2 = fmaf(acc[c][2], sc, sh);
            float v3 = fmaf(acc[c][3], sc, sh);
            float mx = fmaxf(fmaxf(v0,v1), fmaxf(v2,v3));
            g1[(((size_t)im*16 + co) << 10) + (16*h + py)*32 + px] = fmaxf(mx, 0.f);
        }
    }
}

// ---------------- Stage 2: conv2(16->32) MFMA, channel-last hi/lo LDS ----------------
// g1 (1024,16,32,32) -> g2 (1024,32,16,16).  2 blocks/image, 512 thr.
// LDS: imgHi/imgLo ushort [18 rows][34 x][24 ci-pad] (ci 0..15 used).
__global__ __launch_bounds__(512)
void stage2_kernel(const float* __restrict__ g1,
                   const u16* __restrict__ w2hi, const u16* __restrict__ w2lo,
                   const float* __restrict__ cb,
                   const float* __restrict__ bg,
                   const float* __restrict__ bb,
                   const float* __restrict__ bm,
                   const float* __restrict__ bv,
                   float* __restrict__ g2)
{
    __shared__ alignas(16) u16 imgHi[18*34*24];   // 14688
    __shared__ alignas(16) u16 imgLo[18*34*24];
    __shared__ float sscale[32];
    __shared__ float sshift[32];
    const int im = blockIdx.x >> 1;
    const int h  = blockIdx.x & 1;
    const int t  = threadIdx.x;

    // zero both planes (pads must be 0)
    {
        uint32* p0 = (uint32*)imgHi;
        uint32* p1 = (uint32*)imgLo;
        for (int i = t; i < 7344; i += 512) { p0[i] = 0u; p1[i] = 0u; }
    }
    if (t < 32) {
        float inv = bg[t] * rsqrtf(bv[t] + BN_EPS);
        sscale[t] = inv;
        sshift[t] = cb[t]*inv + bb[t] - bm[t]*inv;
    }
    __syncthreads();

    // stage rows gy = 16h-1 .. 16h+16 into channel-last split planes
    const float* gin = g1 + (size_t)im*16384;
    for (int i4 = t; i4 < 2304; i4 += 512) {      // 16ci * 18r * 8x4
        int ci  = ((i4 >> 4)*57) >> 9;            // i4/144
        int rem = i4 - ci*144;
        int r   = rem >> 3;
        int x4  = rem & 7;
        int gy  = 16*h - 1 + r;
        float4 vv = make_float4(0.f,0.f,0.f,0.f);
        if (gy >= 0 && gy < 32)
            vv = *reinterpret_cast<const float4*>(&gin[ci*1024 + gy*32 + 4*x4]);
        int base = (r*34 + 4*x4 + 1)*24 + ci;
        float fv[4] = {vv.x, vv.y, vv.z, vv.w};
        #pragma unroll
        for (int d = 0; d < 4; ++d) {
            u16 hi = f2bf_rne(fv[d]);
            imgHi[base + d*24] = hi;
            imgLo[base + d*24] = f2bf_rne(fv[d] - bf2f(hi));
        }
    }
    __syncthreads();

    const int wv   = __builtin_amdgcn_readfirstlane(t >> 6);  // 0..7
    const int lane = t & 63;
    const int lg   = lane >> 4;
    const int col  = lane & 15;

    f32x4 acc[2][2][2];               // [ct][ntoy][oxh]
    #pragma unroll
    for (int a0 = 0; a0 < 2; ++a0)
        #pragma unroll
        for (int a1 = 0; a1 < 2; ++a1)
            #pragma unroll
            for (int a2 = 0; a2 < 2; ++a2)
                acc[a0][a1][a2] = (f32x4){0.f,0.f,0.f,0.f};

    const short8v* w2h8 = (const short8v*)w2hi;
    const short8v* w2l8 = (const short8v*)w2lo;

    #pragma unroll
    for (int g = 0; g < 5; ++g) {
        short8v ah[2], al[2];
        #pragma unroll
        for (int ct = 0; ct < 2; ++ct) {
            int fidx = ((g*4 + lg)*2 + ct)*16 + col;
            ah[ct] = w2h8[fidx];
            al[ct] = w2l8[fidx];
        }
        int tap = 2*g + (lg >> 1);
        tap = (tap > 8) ? 8 : tap;      // pad k: weights are 0, address just valid
        int ky = (tap*11) >> 5;
        int kx = tap - 3*ky;
        int ci0 = (lg & 1)*8;
        #pragma unroll
        for (int ntoy = 0; ntoy < 2; ++ntoy) {
            #pragma unroll
            for (int oxh = 0; oxh < 2; ++oxh) {
                int addr = ((2*wv + ntoy + ky)*34 + oxh*16 + col + kx)*24 + ci0;
                short8v bh = *(const short8v*)&imgHi[addr];
                short8v bl = *(const short8v*)&imgLo[addr];
                #pragma unroll
                for (int ct = 0; ct < 2; ++ct) {
                    acc[ct][ntoy][oxh] = __builtin_amdgcn_mfma_f32_16x16x32_bf16(
                        ah[ct], bh, acc[ct][ntoy][oxh], 0, 0, 0);
                    acc[ct][ntoy][oxh] = __builtin_amdgcn_mfma_f32_16x16x32_bf16(
                        ah[ct], bl, acc[ct][ntoy][oxh], 0, 0, 0);
                    acc[ct][ntoy][oxh] = __builtin_amdgcn_mfma_f32_16x16x32_bf16(
                        al[ct], bh, acc[ct][ntoy][oxh], 0, 0, 0);
                }
            }
        }
    }

    // epilogue: BN -> pool -> ReLU -> store
    #pragma unroll
    for (int ct = 0; ct < 2; ++ct) {
        #pragma unroll
        for (int oxh = 0; oxh < 2; ++oxh) {
            #pragma unroll
            for (int r = 0; r < 4; ++r) {
                int co = ct*16 + 4*lg + r;
                float sc = sscale[co], sh = sshift[co];
                float v0 = fmaf(acc[ct][0][oxh][r], sc, sh);
                float v1 = fmaf(acc[ct][1][oxh][r], sc, sh);
                float m = fmaxf(v0, v1);
                float o = __shfl_xor(m, 1);
                m = fmaxf(fmaxf(m, o), 0.f);
                if (!(col & 1)) {
                    int px = oxh*8 + (col >> 1);
                    g2[(((size_t)im*32 + co) << 8) + (8*h + wv)*16 + px] = m;
                }
            }
        }
    }
}

// ------- Stage 3: conv3(32->64) MFMA + BN/ReLU/pool + proj + quantum + cls -------
// g2 (1024,32,16,16) -> out (1024,10).  1 block/image, 512 thr.
// LDS: imgHi/imgLo ushort [18 rows][18 x][40 ci-pad] (ci 0..31 used).
__global__ __launch_bounds__(512)
void stage3_kernel(const float* __restrict__ g2,
                   const u16* __restrict__ w3hi, const u16* __restrict__ w3lo,
                   const float* __restrict__ cb,
                   const float* __restrict__ bg,
                   const float* __restrict__ bb,
                   const float* __restrict__ bm,
                   const float* __restrict__ bv,
                   const float* __restrict__ pw,
                   const float* __restrict__ pb,
                   const float* __restrict__ cw,
                   const float* __restrict__ cbias,
                   float* __restrict__ out)
{
    __shared__ alignas(16) u16 imgHi[18*18*40];   // 12960; fbuf (16KB) aliases after conv
    __shared__ alignas(16) u16 imgLo[18*18*40];
    __shared__ float sscale[64];
    __shared__ float sshift[64];
    __shared__ float red[8][4];
    float* fbuf = (float*)imgHi;
    const int b = blockIdx.x;
    const int t = threadIdx.x;

    {
        uint32* p0 = (uint32*)imgHi;
        uint32* p1 = (uint32*)imgLo;
        for (int i = t; i < 6480; i += 512) { p0[i] = 0u; p1[i] = 0u; }
    }
    if (t < 64) {
        float inv = bg[t] * rsqrtf(bv[t] + BN_EPS);
        sscale[t] = inv;
        sshift[t] = cb[t]*inv + bb[t] - bm[t]*inv;
    }
    __syncthreads();

    const float* gin = g2 + (size_t)b*8192;
    #pragma unroll
    for (int k = 0; k < 4; ++k) {
        int i4 = t + k*512;            // 0..2047: ci(32) y(16) x4(4)
        int x4 = i4 & 3;
        int y  = (i4 >> 2) & 15;
        int ci = i4 >> 6;
        float4 vv = *reinterpret_cast<const float4*>(&gin[ci*256 + y*16 + 4*x4]);
        int base = ((y+1)*18 + 4*x4 + 1)*40 + ci;
        float fv[4] = {vv.x, vv.y, vv.z, vv.w};
        #pragma unroll
        for (int d = 0; d < 4; ++d) {
            u16 hi = f2bf_rne(fv[d]);
            imgHi[base + d*40] = hi;
            imgLo[base + d*40] = f2bf_rne(fv[d] - bf2f(hi));
        }
    }
    __syncthreads();

    const int wv   = __builtin_amdgcn_readfirstlane(t >> 6);
    const int lane = t & 63;
    const int lg   = lane >> 4;
    const int col  = lane & 15;

    f32x4 acc[4][2];
    #pragma unroll
    for (int a0 = 0; a0 < 4; ++a0) {
        acc[a0][0] = (f32x4){0.f,0.f,0.f,0.f};
        acc[a0][1] = (f32x4){0.f,0.f,0.f,0.f};
    }

    const short8v* w3h8 = (const short8v*)w3hi;
    const short8v* w3l8 = (const short8v*)w3lo;

    #pragma unroll
    for (int g = 0; g < 9; ++g) {       // tap = g, ci = 8lg+j
        short8v ah[4], al[4];
        #pragma unroll
        for (int ct = 0; ct < 4; ++ct) {
            int fidx = ((g*4 + lg)*4 + ct)*16 + col;
            ah[ct] = w3h8[fidx];
            al[ct] = w3l8[fidx];
        }
        int ky = (g*11) >> 5;
        int kx = g - 3*ky;
        int ci0 = 8*lg;
        #pragma unroll
        for (int ntoy = 0; ntoy < 2; ++ntoy) {
            int addr = ((2*wv + ntoy + ky)*18 + col + kx)*40 + ci0;
            short8v bh = *(const short8v*)&imgHi[addr];
            short8v bl = *(const short8v*)&imgLo[addr];
            #pragma unroll
            for (int ct = 0; ct < 4; ++ct) {
                acc[ct][ntoy] = __builtin_amdgcn_mfma_f32_16x16x32_bf16(
                    ah[ct], bh, acc[ct][ntoy], 0, 0, 0);
                acc[ct][ntoy] = __builtin_amdgcn_mfma_f32_16x16x32_bf16(
                    ah[ct], bl, acc[ct][ntoy], 0, 0, 0);
                acc[ct][ntoy] = __builtin_amdgcn_mfma_f32_16x16x32_bf16(
                    al[ct], bh, acc[ct][ntoy], 0, 0, 0);
            }
        }
    }
    __syncthreads();                  // img reads done; fbuf may overwrite

    #pragma unroll
    for (int ct = 0; ct < 4; ++ct) {
        #pragma unroll
        for (int r = 0; r < 4; ++r) {
            int co = ct*16 + 4*lg + r;
            float sc = sscale[co], sh = sshift[co];
            float v0 = fmaf(acc[ct][0][r], sc, sh);
            float v1 = fmaf(acc[ct][1][r], sc, sh);
            float m = fmaxf(v0, v1);
            float o = __shfl_xor(m, 1);
            m = fmaxf(fmaxf(m, o), 0.f);
            if (!(col & 1))
                fbuf[co*64 + wv*8 + (col >> 1)] = m;
        }
    }
    __syncthreads();

    float z0=0.f, z1=0.f, z2=0.f, z3=0.f;
    #pragma unroll
    for (int k = 0; k < 8; ++k) {
        int j = k*512 + t;
        float fv = fbuf[j];
        z0 = fmaf(fv, pw[        j], z0);
        z1 = fmaf(fv, pw[ 4096 + j], z1);
        z2 = fmaf(fv, pw[ 8192 + j], z2);
        z3 = fmaf(fv, pw[12288 + j], z3);
    }
    #pragma unroll
    for (int off2 = 32; off2 > 0; off2 >>= 1) {
        z0 += __shfl_down(z0, off2);
        z1 += __shfl_down(z1, off2);
        z2 += __shfl_down(z2, off2);
        z3 += __shfl_down(z3, off2);
    }
    if (lane == 0) { red[wv][0]=z0; red[wv][1]=z1; red[wv][2]=z2; red[wv][3]=z3; }
    __syncthreads();

    if (t == 0) {
        float z[4];
        #pragma unroll
        for (int p2 = 0; p2 < 4; ++p2) {
            float s = pb[p2];
            #pragma unroll
            for (int r = 0; r < 8; ++r) s += red[r][p2];
            z[p2] = s;
        }
        float qc[4], qs[4];
        #pragma unroll
        for (int k = 0; k < 4; ++k) {
            float hh = 0.5f * ALPHA * z[k];
            qc[k] = cosf(hh);
            qs[k] = sinf(hh);
        }
        float st[16];
        #pragma unroll
        for (int j = 0; j < 16; ++j) {
            float v0 = ((j>>3)&1) ? qs[0] : qc[0];
            float v1 = ((j>>2)&1) ? qs[1] : qc[1];
            float v2 = ((j>>1)&1) ? qs[2] : qc[2];
            float v3 = ( j    &1) ? qs[3] : qc[3];
            st[j] = v0*v1*v2*v3;
        }
        const int csrc[4] = {0,1,2,3};
        const int ctgt[4] = {1,2,3,0};
        #pragma unroll
        for (int pp = 0; pp < 4; ++pp) {
            float tmp[16];
            #pragma unroll
            for (int idx = 0; idx < 16; ++idx) {
                int bit = (idx >> (3 - csrc[pp])) & 1;
                int src = bit ? (idx ^ (1 << (3 - ctgt[pp]))) : idx;
                tmp[idx] = st[src];
            }
            #pragma unroll
            for (int idx = 0; idx < 16; ++idx) st[idx] = tmp[idx];
        }
        float feat[10];
        #pragma unroll
        for (int f = 0; f < 10; ++f) feat[f] = 0.f;
        #pragma unroll
        for (int j = 0; j < 16; ++j) {
            float pr = st[j]*st[j];
            float s0 = ((j>>3)&1) ? -1.f : 1.f;
            float s1 = ((j>>2)&1) ? -1.f : 1.f;
            float s2 = ((j>>1)&1) ? -1.f : 1.f;
            float s3 = ( j    &1) ? -1.f : 1.f;
            feat[0] += s0*pr;       feat[1] += s1*pr;
            feat[2] += s2*pr;       feat[3] += s3*pr;
            feat[4] += s0*s1*pr;    feat[5] += s0*s2*pr;
            feat[6] += s0*s3*pr;    feat[7] += s1*s2*pr;
            feat[8] += s1*s3*pr;    feat[9] += s2*s3*pr;
        }
        #pragma unroll
        for (int o = 0; o < 10; ++o) {
            float a = cbias[o];
            #pragma unroll
            for (int f = 0; f < 10; ++f) a = fmaf(feat[f], cw[o*10+f], a);
            out[(size_t)b*10 + o] = a;
        }
    }
}

extern "C" void kernel_launch(void* const* d_in, const int* in_sizes, int n_in,
                              void* d_out, int out_size, void* d_ws, size_t ws_size,
                              hipStream_t stream)
{
    const float* x   = (const float*)d_in[0];
    const float* c1w = (const float*)d_in[1];
    const float* c1b = (const float*)d_in[2];
    const float* c2w = (const float*)d_in[3];
    const float* c2b = (const float*)d_in[4];
    const float* c3w = (const float*)d_in[5];
    const float* c3b = (const float*)d_in[6];
    const float* b1g = (const float*)d_in[7];
    const float* b1b = (const float*)d_in[8];
    const float* b1m = (const float*)d_in[9];
    const float* b1v = (const float*)d_in[10];
    const float* b2g = (const float*)d_in[11];
    const float* b2b = (const float*)d_in[12];
    const float* b2m = (const float*)d_in[13];
    const float* b2v = (const float*)d_in[14];
    const float* b3g = (const float*)d_in[15];
    const float* b3b = (const float*)d_in[16];
    const float* b3m = (const float*)d_in[17];
    const float* b3v = (const float*)d_in[18];
    const float* pw  = (const float*)d_in[19];
    const float* pb  = (const float*)d_in[20];
    const float* cw  = (const float*)d_in[21];
    const float* cbv = (const float*)d_in[22];

    char* wsb = (char*)d_ws;
    float* g1 = (float*)wsb;                               // 64 MB
    float* g2 = (float*)(wsb + 67108864);                  // 32 MB
    u16* w2hi = (u16*)(wsb + 100663296);                   // 96 MB + frag arrays (~92 KB)
    u16* w2lo = w2hi + 5120;
    u16* w3hi = w2lo + 5120;
    u16* w3lo = w3hi + 18432;
    float* out = (float*)d_out;

    prep_kernel  <<<  72, 256, 0, stream>>>(c2w, c3w, w2hi, w2lo, w3hi, w3lo);
    stage1_kernel<<<2048, 256, 0, stream>>>(x,  c1w, c1b, b1g, b1b, b1m, b1v, g1);
    stage2_kernel<<<2048, 512, 0, stream>>>(g1, w2hi, w2lo, c2b, b2g, b2b, b2m, b2v, g2);
    stage3_kernel<<<1024, 512, 0, stream>>>(g2, w3hi, w3lo, c3b, b3g, b3b, b3m, b3v,
                                            pw, pb, cw, cbv, out);
}

// Round 8
// 249.041 us; speedup vs baseline: 2.2977x; 1.2334x over previous
//
#include <hip/hip_runtime.h>
#include <math.h>

#define ALPHA 1.57f
#define BN_EPS 1e-5f

typedef __attribute__((ext_vector_type(8))) short short8v;
typedef __attribute__((ext_vector_type(4))) float f32x4;
typedef unsigned int uint32;
typedef unsigned short u16;

__device__ __forceinline__ u16 f2bf_rne(float f) {
    uint32 u = __float_as_uint(f);
    u += 0x7FFFu + ((u >> 16) & 1u);
    return (u16)(u >> 16);
}
__device__ __forceinline__ float bf2f(u16 h) {
    return __uint_as_float(((uint32)h) << 16);
}

// ---------------- Prep: split-bf16 weight fragments (once per call) ----------------
__global__ __launch_bounds__(256)
void prep_kernel(const float* __restrict__ w2, const float* __restrict__ w3,
                 u16* __restrict__ w2hi, u16* __restrict__ w2lo,
                 u16* __restrict__ w3hi, u16* __restrict__ w3lo)
{
    int t = blockIdx.x*256 + threadIdx.x;
    if (t < 5120) {
        int j = t & 7, col = (t>>3)&15, ct = (t>>7)&1, lg = (t>>8)&3, g = t>>10;
        int k = 32*g + 8*lg + j;
        int tap = k >> 4, ci = k & 15;
        float v = (tap < 9) ? w2[(ct*16+col)*144 + ci*9 + tap] : 0.f;
        u16 hi = f2bf_rne(v);
        w2hi[t] = hi;
        w2lo[t] = f2bf_rne(v - bf2f(hi));
    }
    if (t < 18432) {
        int j = t & 7, col = (t>>3)&15, ct = (t>>7)&3, lg = (t>>9)&3, g = t>>11;
        int ci = 8*lg + j;                 // tap = g
        float v = w3[(ct*16+col)*288 + ci*9 + g];
        u16 hi = f2bf_rne(v);
        w3hi[t] = hi;
        w3lo[t] = f2bf_rne(v - bf2f(hi));
    }
}

// ---------------- Stage 1: conv1(3->16) + BN + ReLU + pool2 ----------------
// x (1024,3,64,64) -> g1 (1024,16,32,32)
// v3: 512 thr, 8 waves x 2 co; 54 weights hoisted to registers before pos loop.
__global__ __launch_bounds__(512)
void stage1_kernel(const float* __restrict__ x,
                   const float* __restrict__ w,    // (16,3,3,3)
                   const float* __restrict__ cb,
                   const float* __restrict__ bg,
                   const float* __restrict__ bb,
                   const float* __restrict__ bm,
                   const float* __restrict__ bv,
                   float* __restrict__ g1)
{
    __shared__ float simg[3*34*66];   // half image + halo, col-padded
    __shared__ float sscale[16];
    __shared__ float sshift[16];
    const int im = blockIdx.x >> 1;
    const int h  = blockIdx.x & 1;
    const int t  = threadIdx.x;

    if (t < 204) {                    // zero left/right pad cols
        int ci = t / 68;
        int r2 = t - ci*68;
        int ry = r2 >> 1;
        int col = (r2 & 1) ? 65 : 0;
        simg[ci*2244 + ry*66 + col] = 0.f;
    }
    if (t < 16) {
        float inv = bg[t] * rsqrtf(bv[t] + BN_EPS);
        sscale[t] = inv;
        sshift[t] = cb[t]*inv + bb[t] - bm[t]*inv;
    }

    const float* xin = x + (size_t)im*12288;
    for (int i4 = t; i4 < 1632; i4 += 512) {   // 3*34*64/4
        int e   = i4 * 4;
        int ci  = e / 2176;
        int rem = e - ci*2176;
        int ry  = rem >> 6;
        int cx  = rem & 63;
        int g   = 32*h - 1 + ry;
        float4 vv = make_float4(0.f,0.f,0.f,0.f);
        if (g >= 0 && g < 64)
            vv = *reinterpret_cast<const float4*>(&xin[ci*4096 + g*64 + cx]);
        float* dst = &simg[ci*2244 + ry*66 + cx + 1];
        dst[0]=vv.x; dst[1]=vv.y; dst[2]=vv.z; dst[3]=vv.w;
    }
    __syncthreads();

    const int wv   = __builtin_amdgcn_readfirstlane(t >> 6);  // 0..7
    const int lane = t & 63;
    const int co0  = wv*2, co1 = wv*2 + 1;

    // hoist all 54 weights (wave-uniform -> scalar regs), reused for 8 steps
    float W0[27], W1[27];
    #pragma unroll
    for (int i = 0; i < 27; ++i) {
        W0[i] = w[co0*27 + i];
        W1[i] = w[co1*27 + i];
    }
    const float sc0 = sscale[co0], sh0 = sshift[co0];
    const float sc1 = sscale[co1], sh1 = sshift[co1];

    for (int step = 0; step < 8; ++step) {
        int pos = step*64 + lane;              // 0..511 local pooled position
        int py = pos >> 5, px = pos & 31;
        float a0[4] = {0.f,0.f,0.f,0.f};
        float a1[4] = {0.f,0.f,0.f,0.f};
        #pragma unroll
        for (int ci = 0; ci < 3; ++ci) {
            float p[16];
            const float* sp = &simg[ci*2244 + (2*py)*66 + 2*px];
            #pragma unroll
            for (int i = 0; i < 4; ++i) {
                const float2* sp2 = reinterpret_cast<const float2*>(sp + i*66);
                float2 q0 = sp2[0];
                float2 q1 = sp2[1];
                p[i*4+0]=q0.x; p[i*4+1]=q0.y; p[i*4+2]=q1.x; p[i*4+3]=q1.y;
            }
            #pragma unroll
            for (int ky = 0; ky < 3; ++ky)
                #pragma unroll
                for (int kx = 0; kx < 3; ++kx) {
                    float w0 = W0[ci*9 + ky*3 + kx];
                    float w1 = W1[ci*9 + ky*3 + kx];
                    float e00 = p[ ky   *4+kx  ], e01 = p[ ky   *4+kx+1];
                    float e10 = p[(ky+1)*4+kx  ], e11 = p[(ky+1)*4+kx+1];
                    a0[0] = fmaf(w0, e00, a0[0]);
                    a0[1] = fmaf(w0, e01, a0[1]);
                    a0[2] = fmaf(w0, e10, a0[2]);
                    a0[3] = fmaf(w0, e11, a0[3]);
                    a1[0] = fmaf(w1, e00, a1[0]);
                    a1[1] = fmaf(w1, e01, a1[1]);
                    a1[2] = fmaf(w1, e10, a1[2]);
                    a1[3] = fmaf(w1, e11, a1[3]);
                }
        }
        {
            float v0 = fmaf(a0[0], sc0, sh0);
            float v1 = fmaf(a0[1], sc0, sh0);
            float v2 = fmaf(a0[2], sc0, sh0);
            float v3 = fmaf(a0[3], sc0, sh0);
            float mx = fmaxf(fmaxf(v0,v1), fmaxf(v2,v3));
            g1[(((size_t)im*16 + co0) << 10) + (16*h + py)*32 + px] = fmaxf(mx, 0.f);
            v0 = fmaf(a1[0], sc1, sh1);
            v1 = fmaf(a1[1], sc1, sh1);
            v2 = fmaf(a1[2], sc1, sh1);
            v3 = fmaf(a1[3], sc1, sh1);
            mx = fmaxf(fmaxf(v0,v1), fmaxf(v2,v3));
            g1[(((size_t)im*16 + co1) << 10) + (16*h + py)*32 + px] = fmaxf(mx, 0.f);
        }
    }
}

// ---------------- Stage 2: conv2(16->32) MFMA, channel-last hi/lo LDS ----------------
__global__ __launch_bounds__(512)
void stage2_kernel(const float* __restrict__ g1,
                   const u16* __restrict__ w2hi, const u16* __restrict__ w2lo,
                   const float* __restrict__ cb,
                   const float* __restrict__ bg,
                   const float* __restrict__ bb,
                   const float* __restrict__ bm,
                   const float* __restrict__ bv,
                   float* __restrict__ g2)
{
    __shared__ alignas(16) u16 imgHi[18*34*24];
    __shared__ alignas(16) u16 imgLo[18*34*24];
    __shared__ float sscale[32];
    __shared__ float sshift[32];
    const int im = blockIdx.x >> 1;
    const int h  = blockIdx.x & 1;
    const int t  = threadIdx.x;

    {
        uint32* p0 = (uint32*)imgHi;
        uint32* p1 = (uint32*)imgLo;
        for (int i = t; i < 7344; i += 512) { p0[i] = 0u; p1[i] = 0u; }
    }
    if (t < 32) {
        float inv = bg[t] * rsqrtf(bv[t] + BN_EPS);
        sscale[t] = inv;
        sshift[t] = cb[t]*inv + bb[t] - bm[t]*inv;
    }
    __syncthreads();

    const float* gin = g1 + (size_t)im*16384;
    for (int i4 = t; i4 < 2304; i4 += 512) {
        int ci  = ((i4 >> 4)*57) >> 9;
        int rem = i4 - ci*144;
        int r   = rem >> 3;
        int x4  = rem & 7;
        int gy  = 16*h - 1 + r;
        float4 vv = make_float4(0.f,0.f,0.f,0.f);
        if (gy >= 0 && gy < 32)
            vv = *reinterpret_cast<const float4*>(&gin[ci*1024 + gy*32 + 4*x4]);
        int base = (r*34 + 4*x4 + 1)*24 + ci;
        float fv[4] = {vv.x, vv.y, vv.z, vv.w};
        #pragma unroll
        for (int d = 0; d < 4; ++d) {
            u16 hi = f2bf_rne(fv[d]);
            imgHi[base + d*24] = hi;
            imgLo[base + d*24] = f2bf_rne(fv[d] - bf2f(hi));
        }
    }
    __syncthreads();

    const int wv   = __builtin_amdgcn_readfirstlane(t >> 6);
    const int lane = t & 63;
    const int lg   = lane >> 4;
    const int col  = lane & 15;

    f32x4 acc[2][2][2];
    #pragma unroll
    for (int a0 = 0; a0 < 2; ++a0)
        #pragma unroll
        for (int a1 = 0; a1 < 2; ++a1)
            #pragma unroll
            for (int a2 = 0; a2 < 2; ++a2)
                acc[a0][a1][a2] = (f32x4){0.f,0.f,0.f,0.f};

    const short8v* w2h8 = (const short8v*)w2hi;
    const short8v* w2l8 = (const short8v*)w2lo;

    #pragma unroll
    for (int g = 0; g < 5; ++g) {
        short8v ah[2], al[2];
        #pragma unroll
        for (int ct = 0; ct < 2; ++ct) {
            int fidx = ((g*4 + lg)*2 + ct)*16 + col;
            ah[ct] = w2h8[fidx];
            al[ct] = w2l8[fidx];
        }
        int tap = 2*g + (lg >> 1);
        tap = (tap > 8) ? 8 : tap;
        int ky = (tap*11) >> 5;
        int kx = tap - 3*ky;
        int ci0 = (lg & 1)*8;
        #pragma unroll
        for (int ntoy = 0; ntoy < 2; ++ntoy) {
            #pragma unroll
            for (int oxh = 0; oxh < 2; ++oxh) {
                int addr = ((2*wv + ntoy + ky)*34 + oxh*16 + col + kx)*24 + ci0;
                short8v bh = *(const short8v*)&imgHi[addr];
                short8v bl = *(const short8v*)&imgLo[addr];
                #pragma unroll
                for (int ct = 0; ct < 2; ++ct) {
                    acc[ct][ntoy][oxh] = __builtin_amdgcn_mfma_f32_16x16x32_bf16(
                        ah[ct], bh, acc[ct][ntoy][oxh], 0, 0, 0);
                    acc[ct][ntoy][oxh] = __builtin_amdgcn_mfma_f32_16x16x32_bf16(
                        ah[ct], bl, acc[ct][ntoy][oxh], 0, 0, 0);
                    acc[ct][ntoy][oxh] = __builtin_amdgcn_mfma_f32_16x16x32_bf16(
                        al[ct], bh, acc[ct][ntoy][oxh], 0, 0, 0);
                }
            }
        }
    }

    #pragma unroll
    for (int ct = 0; ct < 2; ++ct) {
        #pragma unroll
        for (int oxh = 0; oxh < 2; ++oxh) {
            #pragma unroll
            for (int r = 0; r < 4; ++r) {
                int co = ct*16 + 4*lg + r;
                float sc = sscale[co], sh = sshift[co];
                float v0 = fmaf(acc[ct][0][oxh][r], sc, sh);
                float v1 = fmaf(acc[ct][1][oxh][r], sc, sh);
                float m = fmaxf(v0, v1);
                float o = __shfl_xor(m, 1);
                m = fmaxf(fmaxf(m, o), 0.f);
                if (!(col & 1)) {
                    int px = oxh*8 + (col >> 1);
                    g2[(((size_t)im*32 + co) << 8) + (8*h + wv)*16 + px] = m;
                }
            }
        }
    }
}

// ------- Stage 3: conv3(32->64) MFMA + BN/ReLU/pool + proj + quantum + cls -------
__global__ __launch_bounds__(512)
void stage3_kernel(const float* __restrict__ g2,
                   const u16* __restrict__ w3hi, const u16* __restrict__ w3lo,
                   const float* __restrict__ cb,
                   const float* __restrict__ bg,
                   const float* __restrict__ bb,
                   const float* __restrict__ bm,
                   const float* __restrict__ bv,
                   const float* __restrict__ pw,
                   const float* __restrict__ pb,
                   const float* __restrict__ cw,
                   const float* __restrict__ cbias,
                   float* __restrict__ out)
{
    __shared__ alignas(16) u16 imgHi[18*18*40];
    __shared__ alignas(16) u16 imgLo[18*18*40];
    __shared__ float sscale[64];
    __shared__ float sshift[64];
    __shared__ float red[8][4];
    float* fbuf = (float*)imgHi;
    const int b = blockIdx.x;
    const int t = threadIdx.x;

    {
        uint32* p0 = (uint32*)imgHi;
        uint32* p1 = (uint32*)imgLo;
        for (int i = t; i < 6480; i += 512) { p0[i] = 0u; p1[i] = 0u; }
    }
    if (t < 64) {
        float inv = bg[t] * rsqrtf(bv[t] + BN_EPS);
        sscale[t] = inv;
        sshift[t] = cb[t]*inv + bb[t] - bm[t]*inv;
    }
    __syncthreads();

    const float* gin = g2 + (size_t)b*8192;
    #pragma unroll
    for (int k = 0; k < 4; ++k) {
        int i4 = t + k*512;
        int x4 = i4 & 3;
        int y  = (i4 >> 2) & 15;
        int ci = i4 >> 6;
        float4 vv = *reinterpret_cast<const float4*>(&gin[ci*256 + y*16 + 4*x4]);
        int base = ((y+1)*18 + 4*x4 + 1)*40 + ci;
        float fv[4] = {vv.x, vv.y, vv.z, vv.w};
        #pragma unroll
        for (int d = 0; d < 4; ++d) {
            u16 hi = f2bf_rne(fv[d]);
            imgHi[base + d*40] = hi;
            imgLo[base + d*40] = f2bf_rne(fv[d] - bf2f(hi));
        }
    }
    __syncthreads();

    const int wv   = __builtin_amdgcn_readfirstlane(t >> 6);
    const int lane = t & 63;
    const int lg   = lane >> 4;
    const int col  = lane & 15;

    f32x4 acc[4][2];
    #pragma unroll
    for (int a0 = 0; a0 < 4; ++a0) {
        acc[a0][0] = (f32x4){0.f,0.f,0.f,0.f};
        acc[a0][1] = (f32x4){0.f,0.f,0.f,0.f};
    }

    const short8v* w3h8 = (const short8v*)w3hi;
    const short8v* w3l8 = (const short8v*)w3lo;

    #pragma unroll
    for (int g = 0; g < 9; ++g) {
        short8v ah[4], al[4];
        #pragma unroll
        for (int ct = 0; ct < 4; ++ct) {
            int fidx = ((g*4 + lg)*4 + ct)*16 + col;
            ah[ct] = w3h8[fidx];
            al[ct] = w3l8[fidx];
        }
        int ky = (g*11) >> 5;
        int kx = g - 3*ky;
        int ci0 = 8*lg;
        #pragma unroll
        for (int ntoy = 0; ntoy < 2; ++ntoy) {
            int addr = ((2*wv + ntoy + ky)*18 + col + kx)*40 + ci0;
            short8v bh = *(const short8v*)&imgHi[addr];
            short8v bl = *(const short8v*)&imgLo[addr];
            #pragma unroll
            for (int ct = 0; ct < 4; ++ct) {
                acc[ct][ntoy] = __builtin_amdgcn_mfma_f32_16x16x32_bf16(
                    ah[ct], bh, acc[ct][ntoy], 0, 0, 0);
                acc[ct][ntoy] = __builtin_amdgcn_mfma_f32_16x16x32_bf16(
                    ah[ct], bl, acc[ct][ntoy], 0, 0, 0);
                acc[ct][ntoy] = __builtin_amdgcn_mfma_f32_16x16x32_bf16(
                    al[ct], bh, acc[ct][ntoy], 0, 0, 0);
            }
        }
    }
    __syncthreads();

    #pragma unroll
    for (int ct = 0; ct < 4; ++ct) {
        #pragma unroll
        for (int r = 0; r < 4; ++r) {
            int co = ct*16 + 4*lg + r;
            float sc = sscale[co], sh = sshift[co];
            float v0 = fmaf(acc[ct][0][r], sc, sh);
            float v1 = fmaf(acc[ct][1][r], sc, sh);
            float m = fmaxf(v0, v1);
            float o = __shfl_xor(m, 1);
            m = fmaxf(fmaxf(m, o), 0.f);
            if (!(col & 1))
                fbuf[co*64 + wv*8 + (col >> 1)] = m;
        }
    }
    __syncthreads();

    float z0=0.f, z1=0.f, z2=0.f, z3=0.f;
    #pragma unroll
    for (int k = 0; k < 8; ++k) {
        int j = k*512 + t;
        float fv = fbuf[j];
        z0 = fmaf(fv, pw[        j], z0);
        z1 = fmaf(fv, pw[ 4096 + j], z1);
        z2 = fmaf(fv, pw[ 8192 + j], z2);
        z3 = fmaf(fv, pw[12288 + j], z3);
    }
    #pragma unroll
    for (int off2 = 32; off2 > 0; off2 >>= 1) {
        z0 += __shfl_down(z0, off2);
        z1 += __shfl_down(z1, off2);
        z2 += __shfl_down(z2, off2);
        z3 += __shfl_down(z3, off2);
    }
    if (lane == 0) { red[wv][0]=z0; red[wv][1]=z1; red[wv][2]=z2; red[wv][3]=z3; }
    __syncthreads();

    if (t == 0) {
        float z[4];
        #pragma unroll
        for (int p2 = 0; p2 < 4; ++p2) {
            float s = pb[p2];
            #pragma unroll
            for (int r = 0; r < 8; ++r) s += red[r][p2];
            z[p2] = s;
        }
        float qc[4], qs[4];
        #pragma unroll
        for (int k = 0; k < 4; ++k) {
            float hh = 0.5f * ALPHA * z[k];
            qc[k] = cosf(hh);
            qs[k] = sinf(hh);
        }
        float st[16];
        #pragma unroll
        for (int j = 0; j < 16; ++j) {
            float v0 = ((j>>3)&1) ? qs[0] : qc[0];
            float v1 = ((j>>2)&1) ? qs[1] : qc[1];
            float v2 = ((j>>1)&1) ? qs[2] : qc[2];
            float v3 = ( j    &1) ? qs[3] : qc[3];
            st[j] = v0*v1*v2*v3;
        }
        const int csrc[4] = {0,1,2,3};
        const int ctgt[4] = {1,2,3,0};
        #pragma unroll
        for (int pp = 0; pp < 4; ++pp) {
            float tmp[16];
            #pragma unroll
            for (int idx = 0; idx < 16; ++idx) {
                int bit = (idx >> (3 - csrc[pp])) & 1;
                int src = bit ? (idx ^ (1 << (3 - ctgt[pp]))) : idx;
                tmp[idx] = st[src];
            }
            #pragma unroll
            for (int idx = 0; idx < 16; ++idx) st[idx] = tmp[idx];
        }
        float feat[10];
        #pragma unroll
        for (int f = 0; f < 10; ++f) feat[f] = 0.f;
        #pragma unroll
        for (int j = 0; j < 16; ++j) {
            float pr = st[j]*st[j];
            float s0 = ((j>>3)&1) ? -1.f : 1.f;
            float s1 = ((j>>2)&1) ? -1.f : 1.f;
            float s2 = ((j>>1)&1) ? -1.f : 1.f;
            float s3 = ( j    &1) ? -1.f : 1.f;
            feat[0] += s0*pr;       feat[1] += s1*pr;
            feat[2] += s2*pr;       feat[3] += s3*pr;
            feat[4] += s0*s1*pr;    feat[5] += s0*s2*pr;
            feat[6] += s0*s3*pr;    feat[7] += s1*s2*pr;
            feat[8] += s1*s3*pr;    feat[9] += s2*s3*pr;
        }
        #pragma unroll
        for (int o = 0; o < 10; ++o) {
            float a = cbias[o];
            #pragma unroll
            for (int f = 0; f < 10; ++f) a = fmaf(feat[f], cw[o*10+f], a);
            out[(size_t)b*10 + o] = a;
        }
    }
}

extern "C" void kernel_launch(void* const* d_in, const int* in_sizes, int n_in,
                              void* d_out, int out_size, void* d_ws, size_t ws_size,
                              hipStream_t stream)
{
    const float* x   = (const float*)d_in[0];
    const float* c1w = (const float*)d_in[1];
    const float* c1b = (const float*)d_in[2];
    const float* c2w = (const float*)d_in[3];
    const float* c2b = (const float*)d_in[4];
    const float* c3w = (const float*)d_in[5];
    const float* c3b = (const float*)d_in[6];
    const float* b1g = (const float*)d_in[7];
    const float* b1b = (const float*)d_in[8];
    const float* b1m = (const float*)d_in[9];
    const float* b1v = (const float*)d_in[10];
    const float* b2g = (const float*)d_in[11];
    const float* b2b = (const float*)d_in[12];
    const float* b2m = (const float*)d_in[13];
    const float* b2v = (const float*)d_in[14];
    const float* b3g = (const float*)d_in[15];
    const float* b3b = (const float*)d_in[16];
    const float* b3m = (const float*)d_in[17];
    const float* b3v = (const float*)d_in[18];
    const float* pw  = (const float*)d_in[19];
    const float* pb  = (const float*)d_in[20];
    const float* cw  = (const float*)d_in[21];
    const float* cbv = (const float*)d_in[22];

    char* wsb = (char*)d_ws;
    float* g1 = (float*)wsb;                               // 64 MB
    float* g2 = (float*)(wsb + 67108864);                  // 32 MB
    u16* w2hi = (u16*)(wsb + 100663296);                   // frag arrays (~92 KB)
    u16* w2lo = w2hi + 5120;
    u16* w3hi = w2lo + 5120;
    u16* w3lo = w3hi + 18432;
    float* out = (float*)d_out;

    prep_kernel  <<<  72, 256, 0, stream>>>(c2w, c3w, w2hi, w2lo, w3hi, w3lo);
    stage1_kernel<<<2048, 512, 0, stream>>>(x,  c1w, c1b, b1g, b1b, b1m, b1v, g1);
    stage2_kernel<<<2048, 512, 0, stream>>>(g1, w2hi, w2lo, c2b, b2g, b2b, b2m, b2v, g2);
    stage3_kernel<<<1024, 512, 0, stream>>>(g2, w3hi, w3lo, c3b, b3g, b3b, b3m, b3v,
                                            pw, pb, cw, cbv, out);
}